// Round 3
// baseline (514.119 us; speedup 1.0000x reference)
//
#include <hip/hip_runtime.h>
#include <hip/hip_cooperative_groups.h>

namespace cg = cooperative_groups;

#define F 128
#define CAP 64    // bucket capacity per node (deg~Poisson(12), P(>64)~1e-30)
#define LDT 136   // sWt leading dim (bf16 elems)
#define TR 64     // fallback GEMM row tile
#define KC 32
#define LDA 36
#define LDW 160

typedef __attribute__((ext_vector_type(8))) short bf16x8;
typedef __attribute__((ext_vector_type(4))) float f32x4;

__device__ __forceinline__ unsigned short bf16r(float f)
{
    unsigned u = __float_as_uint(f);
    return (unsigned short)((u + 0x7fffu + ((u >> 16) & 1u)) >> 16);
}

__device__ __forceinline__ unsigned pack2(float a, float b)
{
    return (unsigned)bf16r(a) | ((unsigned)bf16r(b) << 16);
}

__device__ __forceinline__ void load_edge(const int* __restrict__ ei, int is64,
                                          int E, int e, int& s, int& d)
{
    if (is64) {
        s = reinterpret_cast<const int2*>(ei)[e].x;
        d = reinterpret_cast<const int2*>(ei)[(size_t)E + e].x;
    } else {
        s = ei[e];
        d = ei[E + e];
    }
}

__device__ __forceinline__ float4 bf16x4_to_f4(uint2 u)
{
    float4 f;
    f.x = __uint_as_float(u.x << 16);
    f.y = __uint_as_float(u.x & 0xffff0000u);
    f.z = __uint_as_float(u.y << 16);
    f.w = __uint_as_float(u.y & 0xffff0000u);
    return f;
}

// async 16B/lane global->LDS stage (1 KB per call per wave). LDS dest is
// wave-uniform base + lane*16 (HW rule); global src addr is per-lane.
__device__ __forceinline__ void async_copy16(const void* g, void* lds)
{
    __builtin_amdgcn_global_load_lds(
        (const __attribute__((address_space(1))) unsigned int*)g,
        (__attribute__((address_space(3))) unsigned int*)lds,
        16, 0, 0);
}

// =======================================================================
// tier A: ONE cooperative dispatch, 4 phases, 3 grid syncs.
//   A: zero cursor + W->Wt(bf16,T)        [needs nothing]
//   B: position edges (atomics) + x->bf16 [needs cursor=0]
//   C: async-LDS gather -> aggbf(bf16)    [needs csr16 + xh]
//   D: MFMA GEMM -> out                   [needs aggbf + Wt]
// grid=1024, LDS=34816B, launch_bounds(256,4) => exactly 4 blk/CU.
// =======================================================================
__global__ __launch_bounds__(256, 4) void fused_all_kernel(
    const float* __restrict__ x, const int* __restrict__ ei,
    const float* __restrict__ W, const float* __restrict__ bias,
    float* __restrict__ out, int* __restrict__ cursor,
    unsigned short* __restrict__ csr16, unsigned int* __restrict__ xh,
    unsigned short* __restrict__ Wt, unsigned int* __restrict__ aggbf,
    int N, int E, int M4)
{
    __shared__ __align__(16) char smem[F * LDT * 2];   // 34816 B
    cg::grid_group grid = cg::this_grid();
    const int t   = threadIdx.x;
    const int tid = blockIdx.x * 256 + t;
    const int T   = gridDim.x * 256;

    // ---------------- phase A ----------------
    for (int i = tid; i < N; i += T) cursor[i] = 0;
    for (int i = tid; i < F * F; i += T) {
        int k = i >> 7, n = i & 127;
        Wt[n * F + k] = bf16r(W[i]);
    }
    grid.sync();

    // ---------------- phase B ----------------
    int or_hi = 0;
    {
        int lim = 2 * E; if (lim > 16) lim = 16;
        for (int j = 1; j < lim; j += 2) or_hi |= ei[j];
    }
    const int is64 = (or_hi == 0) ? 1 : 0;

    for (int g4 = tid; g4 * 4 < E; g4 += T) {
        const int base = g4 * 4;
        int s[4], d[4], cnt;
        if (base + 3 < E && (E & 3) == 0) {
            cnt = 4;
            if (is64) {
                const int4* sp = reinterpret_cast<const int4*>(ei);
                int4 a = sp[g4 * 2], b = sp[g4 * 2 + 1];
                s[0] = a.x; s[1] = a.z; s[2] = b.x; s[3] = b.z;
                const int4* dp = reinterpret_cast<const int4*>(ei) + ((size_t)E >> 1);
                int4 c4 = dp[g4 * 2], e4 = dp[g4 * 2 + 1];
                d[0] = c4.x; d[1] = c4.z; d[2] = e4.x; d[3] = e4.z;
            } else {
                int4 sv4 = reinterpret_cast<const int4*>(ei)[g4];
                int4 dv4 = reinterpret_cast<const int4*>(ei + E)[g4];
                s[0] = sv4.x; s[1] = sv4.y; s[2] = sv4.z; s[3] = sv4.w;
                d[0] = dv4.x; d[1] = dv4.y; d[2] = dv4.z; d[3] = dv4.w;
            }
        } else {
            cnt = E - base; if (cnt > 4) cnt = 4;
            for (int j = 0; j < cnt; ++j) load_edge(ei, is64, E, base + j, s[j], d[j]);
            for (int j = cnt; j < 4; ++j) { s[j] = 0; d[j] = 0; }
            goto tail;
        }
        cnt = 4;
    tail:
        int slot[4];
        #pragma unroll
        for (int j = 0; j < 4; ++j)
            slot[j] = (j < cnt) ? atomicAdd(&cursor[d[j]], 1) : CAP;
        #pragma unroll
        for (int j = 0; j < 4; ++j)
            if (slot[j] < CAP) csr16[(size_t)d[j] * CAP + slot[j]] = (unsigned short)s[j];
    }
    for (int i = tid; i < M4; i += T) {
        float4 v = reinterpret_cast<const float4*>(x)[i];
        uint2 o;
        o.x = pack2(v.x, v.y);
        o.y = pack2(v.z, v.w);
        reinterpret_cast<uint2*>(xh)[i] = o;
    }
    grid.sync();

    // ---------------- phase C: gather ----------------
    const int wv = t >> 6, lane = t & 63;
    const int eg = lane >> 4;         // edge-group 0..3 within a 4-edge stage
    const int c  = lane & 15;         // uint4 column: feats 8c..8c+7
    char* ldsW = smem + wv * 4096;    // per-wave 4 KB staging slice
    const int wid   = blockIdx.x * 4 + wv;
    const int wstep = gridDim.x * 4;

    int node = wid;
    int deg = 0, sv = 0;
    if (node < N) {
        deg = cursor[node];
        sv  = (int)csr16[(size_t)node * CAP + lane];
    }
    while (node < N) {
        const int nnode = node + wstep;
        int ndeg = 0, nsv = 0;
        if (nnode < N) {                 // prefetch; completes under vmcnt(0)
            ndeg = cursor[nnode];
            nsv  = (int)csr16[(size_t)nnode * CAP + lane];
        }
        if (deg <= CAP) {
            float f[8];
            #pragma unroll
            for (int j = 0; j < 8; ++j) f[j] = 0.f;
            for (int ch = 0; ch < deg; ch += 16) {
                int nE = deg - ch; if (nE > 16) nE = 16;
                int nL = (nE + 3) >> 2;
                // close LDS WAR (prev ds_reads) before restaging this slice
                asm volatile("s_waitcnt lgkmcnt(0)" ::: "memory");
                __builtin_amdgcn_sched_barrier(0);
                for (int l = 0; l < nL; ++l) {
                    int e = ch + l * 4 + eg;
                    int esel = (e < deg) ? e : (deg - 1);
                    int src = __shfl(sv, esel);
                    async_copy16((const char*)xh + ((size_t)src * 256 + (size_t)c * 16),
                                 ldsW + l * 1024);
                }
                asm volatile("s_waitcnt vmcnt(0)" ::: "memory");
                __builtin_amdgcn_sched_barrier(0);
                for (int l = 0; l < nL; ++l) {
                    uint4 v = *reinterpret_cast<const uint4*>(ldsW + l * 1024 + lane * 16);
                    if (ch + l * 4 + eg < deg) {
                        f[0] += __uint_as_float(v.x << 16);
                        f[1] += __uint_as_float(v.x & 0xffff0000u);
                        f[2] += __uint_as_float(v.y << 16);
                        f[3] += __uint_as_float(v.y & 0xffff0000u);
                        f[4] += __uint_as_float(v.z << 16);
                        f[5] += __uint_as_float(v.z & 0xffff0000u);
                        f[6] += __uint_as_float(v.w << 16);
                        f[7] += __uint_as_float(v.w & 0xffff0000u);
                    }
                }
            }
            #pragma unroll
            for (int j = 0; j < 8; ++j) {
                f[j] += __shfl_xor(f[j], 16);
                f[j] += __shfl_xor(f[j], 32);
            }
            if (eg == 0) {
                uint4 o;
                o.x = pack2(f[0], f[1]);
                o.y = pack2(f[2], f[3]);
                o.z = pack2(f[4], f[5]);
                o.w = pack2(f[6], f[7]);
                reinterpret_cast<uint4*>(aggbf)[(size_t)node * 16 + c] = o;
            }
        } else {
            // overflow (adversarial only): ballot-scan the full edge list
            const int half = lane >> 5, col = lane & 31;
            const uint2* x2 = reinterpret_cast<const uint2*>(xh);
            float4 a0 = make_float4(0.f, 0.f, 0.f, 0.f);
            for (int base = 0; base < E; base += 64) {
                int e = base + lane;
                int ss = 0, dd = -1;
                if (e < E) load_edge(ei, is64, E, e, ss, dd);
                unsigned long long m = __ballot(dd == node);
                while (m) {
                    int i = __ffsll((long long)m) - 1;
                    m &= m - 1;
                    int sb = __shfl(ss, i);
                    float4 v = bf16x4_to_f4(x2[(size_t)sb * 32 + col]);
                    if (half == 0) { a0.x += v.x; a0.y += v.y; a0.z += v.z; a0.w += v.w; }
                }
            }
            a0.x += __shfl_xor(a0.x, 32);
            a0.y += __shfl_xor(a0.y, 32);
            a0.z += __shfl_xor(a0.z, 32);
            a0.w += __shfl_xor(a0.w, 32);
            if (half == 0) {
                uint2 o;
                o.x = pack2(a0.x, a0.y);
                o.y = pack2(a0.z, a0.w);
                reinterpret_cast<uint2*>(aggbf)[(size_t)node * 32 + col] = o;
            }
        }
        node = nnode; deg = ndeg; sv = nsv;
    }
    grid.sync();

    // ---------------- phase D: MFMA GEMM ----------------
    unsigned short* sWt = (unsigned short*)smem;
    const uint4* Wg = reinterpret_cast<const uint4*>(Wt);
    #pragma unroll
    for (int u = 0; u < 8; ++u) {
        int idx = u * 256 + t;        // 0..2047
        int n = idx >> 4;
        int cc = idx & 15;
        *reinterpret_cast<uint4*>(&sWt[n * LDT + cc * 8]) = Wg[idx];
    }
    __syncthreads();

    const int quad = lane >> 4, n15 = lane & 15;
    const unsigned short* agg16 = (const unsigned short*)aggbf;
    for (int tile = blockIdx.x; tile * 64 < N; tile += gridDim.x) {
        const int rbase = tile * 64 + wv * 16;
        f32x4 acc[8];
        #pragma unroll
        for (int i = 0; i < 8; ++i) acc[i] = (f32x4){0.f, 0.f, 0.f, 0.f};

        const int arow = rbase + n15;
        const bool aval = (arow < N);
        #pragma unroll
        for (int kc = 0; kc < F; kc += 32) {
            bf16x8 af;
            if (aval)
                af = *reinterpret_cast<const bf16x8*>(agg16 + (size_t)arow * F + kc + quad * 8);
            else
                af = (bf16x8){0, 0, 0, 0, 0, 0, 0, 0};
            #pragma unroll
            for (int nt = 0; nt < 8; ++nt) {
                bf16x8 bfr = *reinterpret_cast<const bf16x8*>(
                    &sWt[(nt * 16 + n15) * LDT + kc + quad * 8]);
                acc[nt] = __builtin_amdgcn_mfma_f32_16x16x32_bf16(af, bfr, acc[nt], 0, 0, 0);
            }
        }

        #pragma unroll
        for (int nt = 0; nt < 8; ++nt) {
            float bv = bias[nt * 16 + n15];
            #pragma unroll
            for (int reg = 0; reg < 4; ++reg) {
                int row = rbase + quad * 4 + reg;
                if (row < N)
                    out[(size_t)row * F + nt * 16 + n15] = acc[nt][reg] + bv;
            }
        }
    }
}

// ============ tier A fallback (4 dispatches, proven) ============
__global__ __launch_bounds__(256) void prep_kernel(
    const int* __restrict__ ei, const float* __restrict__ x,
    const float* __restrict__ W, int* __restrict__ flag,
    int* __restrict__ cursor, unsigned int* __restrict__ xh,
    unsigned short* __restrict__ Wt, int N, int M4)
{
    int i = blockIdx.x * 256 + threadIdx.x;
    if (i < M4) {
        float4 v = reinterpret_cast<const float4*>(x)[i];
        uint2 o;
        o.x = pack2(v.x, v.y);
        o.y = pack2(v.z, v.w);
        reinterpret_cast<uint2*>(xh)[i] = o;
    }
    if (i < N) cursor[i] = 0;
    if (i < F * F) {
        int k = i >> 7, n = i & 127;
        Wt[n * F + k] = bf16r(W[i]);
    }
    if (i == 0) {
        int or_hi = ei[1] | ei[3] | ei[5] | ei[7] | ei[9] | ei[11] | ei[13] | ei[15];
        *flag = (or_hi == 0) ? 1 : 0;
    }
}

__global__ __launch_bounds__(256) void position4_kernel(
    const int* __restrict__ ei, const int* __restrict__ flag_p,
    int* __restrict__ cursor, unsigned short* __restrict__ csr16, int E)
{
    const int tid = blockIdx.x * 256 + threadIdx.x;
    const int base = 4 * tid;
    if (base >= E) return;
    const int is64 = *flag_p;

    int s[4], d[4];
    int cnt;
    if (base + 3 < E && (E & 3) == 0) {
        cnt = 4;
        if (is64) {
            const int4* sp = reinterpret_cast<const int4*>(ei);
            int4 a = sp[tid * 2], b = sp[tid * 2 + 1];
            s[0] = a.x; s[1] = a.z; s[2] = b.x; s[3] = b.z;
            const int4* dp = reinterpret_cast<const int4*>(ei) + ((size_t)E >> 1);
            int4 c = dp[tid * 2], e4 = dp[tid * 2 + 1];
            d[0] = c.x; d[1] = c.z; d[2] = e4.x; d[3] = e4.z;
        } else {
            int4 sv = reinterpret_cast<const int4*>(ei)[tid];
            int4 dv = reinterpret_cast<const int4*>(ei + E)[tid];
            s[0] = sv.x; s[1] = sv.y; s[2] = sv.z; s[3] = sv.w;
            d[0] = dv.x; d[1] = dv.y; d[2] = dv.z; d[3] = dv.w;
        }
    } else {
        cnt = E - base; if (cnt > 4) cnt = 4;
        for (int j = 0; j < cnt; ++j) load_edge(ei, is64, E, base + j, s[j], d[j]);
        for (int j = cnt; j < 4; ++j) { s[j] = 0; d[j] = 0; }
    }

    int slot[4];
    #pragma unroll
    for (int j = 0; j < 4; ++j)
        slot[j] = (j < cnt) ? atomicAdd(&cursor[d[j]], 1) : CAP;
    #pragma unroll
    for (int j = 0; j < 4; ++j)
        if (slot[j] < CAP) csr16[(size_t)d[j] * CAP + slot[j]] = (unsigned short)s[j];
}

__global__ __launch_bounds__(256, 8) void gather_async_kernel(
    const unsigned int* __restrict__ xh, const int* __restrict__ ei,
    const int* __restrict__ flag_p, const int* __restrict__ cursor,
    const unsigned short* __restrict__ csr16, unsigned int* __restrict__ aggbf,
    int N, int E)
{
    __shared__ char stg[4][4096];
    const int node = blockIdx.x * 4 + (threadIdx.x >> 6);
    if (node >= N) return;
    const int wv   = threadIdx.x >> 6;
    const int lane = threadIdx.x & 63;
    const int eg   = lane >> 4;
    const int c    = lane & 15;
    char* ldsW = &stg[wv][0];

    const int deg = cursor[node];

    if (deg <= CAP) {
        int sv = (lane < deg) ? (int)csr16[(size_t)node * CAP + lane] : 0;
        float f[8];
        #pragma unroll
        for (int j = 0; j < 8; ++j) f[j] = 0.f;

        for (int ch = 0; ch < deg; ch += 16) {
            int nE = deg - ch; if (nE > 16) nE = 16;
            int nL = (nE + 3) >> 2;
            if (ch > 0) {
                asm volatile("s_waitcnt lgkmcnt(0)" ::: "memory");
                __builtin_amdgcn_sched_barrier(0);
            }
            for (int l = 0; l < nL; ++l) {
                int e = ch + l * 4 + eg;
                int esel = (e < deg) ? e : (deg - 1);
                int src = __shfl(sv, esel);
                async_copy16((const char*)xh + ((size_t)src * 256 + (size_t)c * 16),
                             ldsW + l * 1024);
            }
            asm volatile("s_waitcnt vmcnt(0)" ::: "memory");
            __builtin_amdgcn_sched_barrier(0);
            for (int l = 0; l < nL; ++l) {
                uint4 v = *reinterpret_cast<const uint4*>(ldsW + l * 1024 + lane * 16);
                if (ch + l * 4 + eg < deg) {
                    f[0] += __uint_as_float(v.x << 16);
                    f[1] += __uint_as_float(v.x & 0xffff0000u);
                    f[2] += __uint_as_float(v.y << 16);
                    f[3] += __uint_as_float(v.y & 0xffff0000u);
                    f[4] += __uint_as_float(v.z << 16);
                    f[5] += __uint_as_float(v.z & 0xffff0000u);
                    f[6] += __uint_as_float(v.w << 16);
                    f[7] += __uint_as_float(v.w & 0xffff0000u);
                }
            }
        }
        #pragma unroll
        for (int j = 0; j < 8; ++j) {
            f[j] += __shfl_xor(f[j], 16);
            f[j] += __shfl_xor(f[j], 32);
        }
        if (eg == 0) {
            uint4 o;
            o.x = pack2(f[0], f[1]);
            o.y = pack2(f[2], f[3]);
            o.z = pack2(f[4], f[5]);
            o.w = pack2(f[6], f[7]);
            reinterpret_cast<uint4*>(aggbf)[(size_t)node * 16 + c] = o;
        }
    } else {
        const int half = lane >> 5, col = lane & 31;
        const uint2* x2 = reinterpret_cast<const uint2*>(xh);
        int is64 = *flag_p;
        float4 a0 = make_float4(0.f, 0.f, 0.f, 0.f);
        for (int base = 0; base < E; base += 64) {
            int e = base + lane;
            int s = 0, d = -1;
            if (e < E) load_edge(ei, is64, E, e, s, d);
            unsigned long long m = __ballot(d == node);
            while (m) {
                int i = __ffsll((long long)m) - 1;
                m &= m - 1;
                int sb = __shfl(s, i);
                float4 v = bf16x4_to_f4(x2[(size_t)sb * 32 + col]);
                if (half == 0) { a0.x += v.x; a0.y += v.y; a0.z += v.z; a0.w += v.w; }
            }
        }
        a0.x += __shfl_xor(a0.x, 32);
        a0.y += __shfl_xor(a0.y, 32);
        a0.z += __shfl_xor(a0.z, 32);
        a0.w += __shfl_xor(a0.w, 32);
        if (half == 0) {
            uint2 o;
            o.x = pack2(a0.x, a0.y);
            o.y = pack2(a0.z, a0.w);
            reinterpret_cast<uint2*>(aggbf)[(size_t)node * 32 + col] = o;
        }
    }
}

__global__ __launch_bounds__(256) void gemm_mfma_kernel(
    const unsigned short* __restrict__ aggbf, const unsigned short* __restrict__ Wt,
    const float* __restrict__ bias, float* __restrict__ out, int N)
{
    __shared__ unsigned short sWt[F * LDT];
    const int t = threadIdx.x;

    const uint4* Wg = reinterpret_cast<const uint4*>(Wt);
    #pragma unroll
    for (int u = 0; u < 8; ++u) {
        int idx = u * 256 + t;
        int n = idx >> 4;
        int c = idx & 15;
        *reinterpret_cast<uint4*>(&sWt[n * LDT + c * 8]) = Wg[idx];
    }
    __syncthreads();

    const int wv = t >> 6, lane = t & 63;
    const int quad = lane >> 4, n15 = lane & 15;
    const int rbase = blockIdx.x * 64 + wv * 16;

    f32x4 acc[8];
    #pragma unroll
    for (int i = 0; i < 8; ++i) acc[i] = (f32x4){0.f, 0.f, 0.f, 0.f};

    const int arow = rbase + n15;
    const bool aval = (arow < N);
    #pragma unroll
    for (int kc = 0; kc < F; kc += 32) {
        bf16x8 af;
        if (aval)
            af = *reinterpret_cast<const bf16x8*>(aggbf + (size_t)arow * F + kc + quad * 8);
        else
            af = (bf16x8){0, 0, 0, 0, 0, 0, 0, 0};
        #pragma unroll
        for (int nt = 0; nt < 8; ++nt) {
            bf16x8 bfr = *reinterpret_cast<const bf16x8*>(
                &sWt[(nt * 16 + n15) * LDT + kc + quad * 8]);
            acc[nt] = __builtin_amdgcn_mfma_f32_16x16x32_bf16(af, bfr, acc[nt], 0, 0, 0);
        }
    }

    #pragma unroll
    for (int nt = 0; nt < 8; ++nt) {
        float bv = bias[nt * 16 + n15];
        #pragma unroll
        for (int reg = 0; reg < 4; ++reg) {
            int row = rbase + quad * 4 + reg;
            if (row < N)
                out[(size_t)row * F + nt * 16 + n15] = acc[nt][reg] + bv;
        }
    }
}

// ================= fallback tiers (smaller ws or huge N) =================
__global__ __launch_bounds__(256) void init_kernel(
    const int* __restrict__ ei, int* __restrict__ flag,
    int* __restrict__ zero_arr, int N)
{
    int i = blockIdx.x * 256 + threadIdx.x;
    if (i < N) zero_arr[i] = 0;
    if (i == 0) {
        int or_hi = ei[1] | ei[3] | ei[5] | ei[7] | ei[9] | ei[11] | ei[13] | ei[15];
        *flag = (or_hi == 0) ? 1 : 0;
    }
}

__global__ __launch_bounds__(256) void position_bucket_kernel(
    const int* __restrict__ ei, const int* __restrict__ flag_p,
    int* __restrict__ cursor, int* __restrict__ csr_src, int E)
{
    int e = blockIdx.x * 256 + threadIdx.x;
    if (e >= E) return;
    int s, d;
    load_edge(ei, *flag_p, E, e, s, d);
    int slot = atomicAdd(&cursor[d], 1);
    if (slot < CAP) csr_src[(size_t)d * CAP + slot] = s;
}

__global__ __launch_bounds__(256) void gather_bucket_f32_kernel(
    const float* __restrict__ x, const int* __restrict__ ei,
    const int* __restrict__ flag_p, const int* __restrict__ cursor,
    const int* __restrict__ csr_src, float* __restrict__ agg, int N, int E)
{
    int node = blockIdx.x * 4 + (threadIdx.x >> 6);
    if (node >= N) return;
    int lane = threadIdx.x & 63;
    int half = lane >> 5;
    int col = lane & 31;
    int deg = cursor[node];

    const float4* x4 = reinterpret_cast<const float4*>(x);
    float4 a0 = make_float4(0.f, 0.f, 0.f, 0.f);
    float4 a1 = make_float4(0.f, 0.f, 0.f, 0.f);

    if (deg <= CAP) {
        int sv = (lane < deg) ? csr_src[(size_t)node * CAP + lane] : 0;
        int i = 0;
        for (; i + 3 < deg; i += 4) {
            int e0 = __shfl(sv, i + half);
            int e1 = __shfl(sv, i + 2 + half);
            float4 v0 = x4[(size_t)e0 * 32 + col];
            float4 v1 = x4[(size_t)e1 * 32 + col];
            a0.x += v0.x; a0.y += v0.y; a0.z += v0.z; a0.w += v0.w;
            a1.x += v1.x; a1.y += v1.y; a1.z += v1.z; a1.w += v1.w;
        }
        for (; i + 1 < deg; i += 2) {
            int e0 = __shfl(sv, i + half);
            float4 v0 = x4[(size_t)e0 * 32 + col];
            a0.x += v0.x; a0.y += v0.y; a0.z += v0.z; a0.w += v0.w;
        }
        if (i < deg) {
            int e0 = __shfl(sv, i);
            if (half == 0) {
                float4 v = x4[(size_t)e0 * 32 + col];
                a0.x += v.x; a0.y += v.y; a0.z += v.z; a0.w += v.w;
            }
        }
    } else {
        int is64 = *flag_p;
        for (int base = 0; base < E; base += 64) {
            int e = base + lane;
            int s = 0, d = -1;
            if (e < E) load_edge(ei, is64, E, e, s, d);
            unsigned long long m = __ballot(d == node);
            while (m) {
                int i = __ffsll((long long)m) - 1;
                m &= m - 1;
                int sb = __shfl(s, i);
                float4 v = x4[(size_t)sb * 32 + col];
                if (half == 0) { a0.x += v.x; a0.y += v.y; a0.z += v.z; a0.w += v.w; }
            }
        }
    }
    a0.x += a1.x; a0.y += a1.y; a0.z += a1.z; a0.w += a1.w;
    a0.x += __shfl_xor(a0.x, 32);
    a0.y += __shfl_xor(a0.y, 32);
    a0.z += __shfl_xor(a0.z, 32);
    a0.w += __shfl_xor(a0.w, 32);
    if (half == 0)
        reinterpret_cast<float4*>(agg)[(size_t)node * 32 + col] = a0;
}

__global__ __launch_bounds__(256) void scatter_kernel(
    const float* __restrict__ x, const int* __restrict__ ei,
    const int* __restrict__ flag_p, float* __restrict__ agg, int E)
{
    int tid = blockIdx.x * 256 + threadIdx.x;
    int e = tid >> 5;
    if (e >= E) return;
    int c = (tid & 31) << 2;
    int s, d;
    load_edge(ei, *flag_p, E, e, s, d);
    float4 v = *reinterpret_cast<const float4*>(x + (size_t)s * F + c);
    float* o = agg + (size_t)d * F + c;
    unsafeAtomicAdd(o + 0, v.x);
    unsafeAtomicAdd(o + 1, v.y);
    unsafeAtomicAdd(o + 2, v.z);
    unsafeAtomicAdd(o + 3, v.w);
}

__global__ __launch_bounds__(256) void gemm_kernel(
    float* __restrict__ io, const float* __restrict__ W,
    const float* __restrict__ bias, int N)
{
    __shared__ float sA[TR * LDA];
    __shared__ float sW[KC * LDW];
    const int t = threadIdx.x;
    const int row0 = blockIdx.x * TR;
    const int g = t & 7;
    const int r = t >> 3;

    float acc[2][16];
    #pragma unroll
    for (int i = 0; i < 2; ++i)
        #pragma unroll
        for (int j = 0; j < 16; ++j) acc[i][j] = 0.0f;

    for (int kc = 0; kc < F; kc += KC) {
        #pragma unroll
        for (int u = 0; u < 2; ++u) {
            int idx = u * 256 + t;
            int row = idx >> 3;
            int k4 = (idx & 7) * 4;
            int grow = row0 + row;
            float4 v = (grow < N)
                ? *reinterpret_cast<const float4*>(io + (size_t)grow * F + kc + k4)
                : make_float4(0.f, 0.f, 0.f, 0.f);
            *reinterpret_cast<float4*>(&sA[row * LDA + k4]) = v;
        }
        #pragma unroll
        for (int u = 0; u < 4; ++u) {
            int idx = u * 256 + t;
            int kk = idx >> 5;
            int f4 = (idx & 31) * 4;
            float4 v = *reinterpret_cast<const float4*>(W + (size_t)(kc + kk) * F + f4);
            int chunk = f4 >> 4;
            int within = f4 & 15;
            *reinterpret_cast<float4*>(&sW[kk * LDW + chunk * 20 + within]) = v;
        }
        __syncthreads();

        #pragma unroll 8
        for (int kk = 0; kk < KC; ++kk) {
            const float* wp = &sW[kk * LDW + g * 20];
            const float4 w0 = *reinterpret_cast<const float4*>(wp + 0);
            const float4 w1 = *reinterpret_cast<const float4*>(wp + 4);
            const float4 w2 = *reinterpret_cast<const float4*>(wp + 8);
            const float4 w3 = *reinterpret_cast<const float4*>(wp + 12);
            #pragma unroll
            for (int i = 0; i < 2; ++i) {
                const float xv = sA[(r * 2 + i) * LDA + kk];
                acc[i][0]  += xv * w0.x;  acc[i][1]  += xv * w0.y;
                acc[i][2]  += xv * w0.z;  acc[i][3]  += xv * w0.w;
                acc[i][4]  += xv * w1.x;  acc[i][5]  += xv * w1.y;
                acc[i][6]  += xv * w1.z;  acc[i][7]  += xv * w1.w;
                acc[i][8]  += xv * w2.x;  acc[i][9]  += xv * w2.y;
                acc[i][10] += xv * w2.z;  acc[i][11] += xv * w2.w;
                acc[i][12] += xv * w3.x;  acc[i][13] += xv * w3.y;
                acc[i][14] += xv * w3.z;  acc[i][15] += xv * w3.w;
            }
        }
        __syncthreads();
    }

    float bv[16];
    #pragma unroll
    for (int j = 0; j < 16; ++j) bv[j] = bias[g * 16 + j];
    #pragma unroll
    for (int i = 0; i < 2; ++i) {
        int row = row0 + r * 2 + i;
        if (row < N) {
            float* o = io + (size_t)row * F + g * 16;
            #pragma unroll
            for (int j4 = 0; j4 < 4; ++j4) {
                float4 v;
                v.x = acc[i][j4 * 4 + 0] + bv[j4 * 4 + 0];
                v.y = acc[i][j4 * 4 + 1] + bv[j4 * 4 + 1];
                v.z = acc[i][j4 * 4 + 2] + bv[j4 * 4 + 2];
                v.w = acc[i][j4 * 4 + 3] + bv[j4 * 4 + 3];
                *reinterpret_cast<float4*>(o + j4 * 4) = v;
            }
        }
    }
}

extern "C" void kernel_launch(void* const* d_in, const int* in_sizes, int n_in,
                              void* d_out, int out_size, void* d_ws, size_t ws_size,
                              hipStream_t stream) {
    const float* x  = (const float*)d_in[0];
    const int*   ei = (const int*)d_in[1];
    const float* W2 = (const float*)d_in[5];
    const float* b2 = (const float*)d_in[6];
    float* out = (float*)d_out;

    const int N = in_sizes[0] / F;   // 50000
    const int E = in_sizes[2];       // 600000
    const int nblk = (N + 255) / 256;
    const int M = N * (F / 2);       // bf16-pair (u32) count for x
    const int M4 = N * (F / 4);      // float4 count for x
    const int eblk = (E + 255) / 256;

    int* ws = (int*)d_ws;
    // tier A: flag[16] i32, cursor[N] i32, csr16[N*CAP] u16, xh[M] u32,
    //         Wt[F*F] u16, aggbf[N*F/2] u32      (requires N <= 65536)
    size_t needA = (size_t)16 * 4 + (size_t)N * 4 + (size_t)N * CAP * 2
                 + (size_t)M * 4 + (size_t)F * F * 2 + (size_t)N * (F / 2) * 4;
    // tier B: flag[16], cursor[N], csr_src[N*CAP] i32
    size_t needB = (size_t)(16 + N + (size_t)N * CAP) * sizeof(int);

    if (ws_size >= needA && N <= 65536) {
        int* flag    = ws;
        int* cursor  = flag + 16;
        unsigned short* csr16 = (unsigned short*)(cursor + N);
        unsigned int*   xh    = (unsigned int*)(csr16 + (size_t)N * CAP);
        unsigned short* Wt    = (unsigned short*)(xh + M);
        unsigned int*   aggbf = (unsigned int*)(Wt + F * F);

        // ---- single cooperative dispatch (grid=1024, 4 blk/CU by construction)
        int Nv = N, Ev = E, M4v = M4;
        void* args[] = {
            (void*)&x, (void*)&ei, (void*)&W2, (void*)&b2, (void*)&out,
            (void*)&cursor, (void*)&csr16, (void*)&xh, (void*)&Wt, (void*)&aggbf,
            (void*)&Nv, (void*)&Ev, (void*)&M4v
        };
        hipError_t cerr = hipLaunchCooperativeKernel(
            (const void*)fused_all_kernel, dim3(1024), dim3(256), args, 0, stream);
        if (cerr == hipSuccess) return;

        // ---- fallback: proven 4-dispatch path
        int pmax = M4; if (N > pmax) pmax = N; if (F * F > pmax) pmax = F * F;
        prep_kernel<<<(pmax + 255) / 256, 256, 0, stream>>>(
            ei, x, W2, flag, cursor, xh, Wt, N, M4);
        int pblk = ((E + 3) / 4 + 255) / 256;
        position4_kernel<<<pblk, 256, 0, stream>>>(ei, flag, cursor, csr16, E);
        gather_async_kernel<<<(N + 3) / 4, 256, 0, stream>>>(
            xh, ei, flag, cursor, csr16, aggbf, N, E);
        gemm_mfma_kernel<<<(N + 63) / 64, 256, 0, stream>>>(
            (const unsigned short*)aggbf, Wt, b2, out, N);
    } else if (ws_size >= needB) {
        int* flag    = ws;
        int* cursor  = flag + 16;
        int* csr_src = cursor + N;
        init_kernel<<<nblk, 256, 0, stream>>>(ei, flag, cursor, N);
        position_bucket_kernel<<<eblk, 256, 0, stream>>>(ei, flag, cursor, csr_src, E);
        gather_bucket_f32_kernel<<<(N + 3) / 4, 256, 0, stream>>>(
            x, ei, flag, cursor, csr_src, out, N, E);
        gemm_kernel<<<(N + TR - 1) / TR, 256, 0, stream>>>(out, W2, b2, N);
    } else {
        int* flag = ws;
        init_kernel<<<1, 64, 0, stream>>>(ei, flag, flag + 16, 0);
        hipMemsetAsync(out, 0, (size_t)N * F * sizeof(float), stream);
        scatter_kernel<<<(E * 32 + 255) / 256, 256, 0, stream>>>(x, ei, flag, out, E);
        gemm_kernel<<<(N + TR - 1) / TR, 256, 0, stream>>>(out, W2, b2, N);
    }
}

// Round 4
// 168.807 us; speedup vs baseline: 3.0456x; 3.0456x over previous
//
#include <hip/hip_runtime.h>

#define F 128
#define CAP 64    // bucket capacity per node (deg~Poisson(12), P(>64)~1e-30)
#define LDT 136   // A-tile leading dim in bf16 elems (272 B rows, bank-friendly)
#define TR 64     // fallback GEMM row tile
#define KC 32
#define LDA 36
#define LDW 160

typedef __attribute__((ext_vector_type(8))) short bf16x8;
typedef __attribute__((ext_vector_type(4))) float f32x4;

__device__ __forceinline__ unsigned short bf16r(float f)
{
    unsigned u = __float_as_uint(f);
    return (unsigned short)((u + 0x7fffu + ((u >> 16) & 1u)) >> 16);
}

__device__ __forceinline__ unsigned pack2(float a, float b)
{
    return (unsigned)bf16r(a) | ((unsigned)bf16r(b) << 16);
}

__device__ __forceinline__ void load_edge(const int* __restrict__ ei, int is64,
                                          int E, int e, int& s, int& d)
{
    if (is64) {
        s = reinterpret_cast<const int2*>(ei)[e].x;
        d = reinterpret_cast<const int2*>(ei)[(size_t)E + e].x;
    } else {
        s = ei[e];
        d = ei[E + e];
    }
}

__device__ __forceinline__ float4 bf16x4_to_f4(uint2 u)
{
    float4 f;
    f.x = __uint_as_float(u.x << 16);
    f.y = __uint_as_float(u.x & 0xffff0000u);
    f.z = __uint_as_float(u.y << 16);
    f.w = __uint_as_float(u.y & 0xffff0000u);
    return f;
}

// async 16B/lane global->LDS stage (1 KB per call per wave). LDS dest is
// wave-uniform base + lane*16 (HW rule); global src addr is per-lane.
__device__ __forceinline__ void async_copy16(const void* g, void* lds)
{
    __builtin_amdgcn_global_load_lds(
        (const __attribute__((address_space(1))) unsigned int*)g,
        (__attribute__((address_space(3))) unsigned int*)lds,
        16, 0, 0);
}

// ---------- tier A kernel 1: fused prep (x->bf16, W->W^T bf16) + positioning.
// cursor pre-zeroed by hipMemsetAsync. 4 edges/thread, 4 indep atomic chains.
__global__ __launch_bounds__(256) void prep_pos_kernel(
    const int* __restrict__ ei, const float* __restrict__ x,
    const float* __restrict__ W, int* __restrict__ cursor,
    unsigned short* __restrict__ csr16, unsigned int* __restrict__ xh,
    unsigned short* __restrict__ Wt, int N, int E, int M4)
{
    const int tid = blockIdx.x * 256 + threadIdx.x;

    // x -> bf16, float4 (16B) loads, uint2 (8B) stores
    if (tid < M4) {
        float4 v = reinterpret_cast<const float4*>(x)[tid];
        uint2 o;
        o.x = pack2(v.x, v.y);
        o.y = pack2(v.z, v.w);
        reinterpret_cast<uint2*>(xh)[tid] = o;
    }
    // W -> Wt (transposed, bf16)
    if (tid < F * F) {
        int k = tid >> 7, n = tid & 127;
        Wt[n * F + k] = bf16r(W[tid]);
    }

    // edge positioning
    const int base = 4 * tid;
    if (base >= E) return;
    int or_hi = 0;
    {
        int lim = 2 * E; if (lim > 16) lim = 16;
        for (int j = 1; j < lim; j += 2) or_hi |= ei[j];
    }
    const int is64 = (or_hi == 0) ? 1 : 0;

    int s[4], d[4];
    int cnt;
    if (base + 3 < E && (E & 3) == 0) {
        cnt = 4;
        if (is64) {
            const int4* sp = reinterpret_cast<const int4*>(ei);
            int4 a = sp[tid * 2], b = sp[tid * 2 + 1];
            s[0] = a.x; s[1] = a.z; s[2] = b.x; s[3] = b.z;
            const int4* dp = reinterpret_cast<const int4*>(ei) + ((size_t)E >> 1);
            int4 c = dp[tid * 2], e4 = dp[tid * 2 + 1];
            d[0] = c.x; d[1] = c.z; d[2] = e4.x; d[3] = e4.z;
        } else {
            int4 sv = reinterpret_cast<const int4*>(ei)[tid];
            int4 dv = reinterpret_cast<const int4*>(ei + E)[tid];
            s[0] = sv.x; s[1] = sv.y; s[2] = sv.z; s[3] = sv.w;
            d[0] = dv.x; d[1] = dv.y; d[2] = dv.z; d[3] = dv.w;
        }
    } else {
        cnt = E - base; if (cnt > 4) cnt = 4;
        for (int j = 0; j < cnt; ++j) load_edge(ei, is64, E, base + j, s[j], d[j]);
        for (int j = cnt; j < 4; ++j) { s[j] = 0; d[j] = 0; }
    }

    int slot[4];
    #pragma unroll
    for (int j = 0; j < 4; ++j)
        slot[j] = (j < cnt) ? atomicAdd(&cursor[d[j]], 1) : CAP;
    #pragma unroll
    for (int j = 0; j < 4; ++j)
        if (slot[j] < CAP) csr16[(size_t)d[j] * CAP + slot[j]] = (unsigned short)s[j];
}

// ---------- tier A kernel 2: fused gather + MFMA GEMM, 1-wave blocks.
// Block = 64 threads = 1 wave = 16 nodes. grid = ceil(N/16) = 3125 blocks,
// all co-resident (16 blk/CU, LDS 8.5 KB, VGPR<=128 via launch_bounds(64,4)).
// Gather: async global->LDS staging (R2-proven), sv prefetch across nodes.
// A-tile (16 x 272B, bf16) in LDS; B-frags read from global Wt (L1-resident);
// no barriers, no fences, no aggbf round-trip.
__global__ __launch_bounds__(64, 4) void gather_gemm64_kernel(
    const unsigned int* __restrict__ xh, const int* __restrict__ ei,
    const int* __restrict__ cursor, const unsigned short* __restrict__ csr16,
    const unsigned short* __restrict__ Wt, const float* __restrict__ bias,
    float* __restrict__ out, int N, int E)
{
    __shared__ __align__(16) char stg[4096];              // 16-edge staging
    __shared__ __align__(16) unsigned short sA[16][LDT];  // 4352 B A-tile
    const int lane = threadIdx.x;       // 0..63
    const int eg = lane >> 4;           // edge-group within a 4-edge stage
    const int c  = lane & 15;           // uint4 column: feats 8c..8c+7
    const int nbase = blockIdx.x * 16;

    // preload the block's 16 node degrees (lanes 0..15)
    int degl = 0;
    if (lane < 16 && nbase + lane < N) degl = cursor[nbase + lane];

    // ---- gather phase: 16 nodes, software-pipelined sv loads ----
    int deg = __shfl(degl, 0);
    int sv = 0;
    if (nbase < N) sv = (int)csr16[(size_t)nbase * CAP + lane];

    for (int ni = 0; ni < 16; ++ni) {
        const int node = nbase + ni;
        const int nnode = node + 1;
        int ndeg = (ni < 15) ? __shfl(degl, ni + 1) : 0;
        int nsv = 0;
        if (ni < 15 && nnode < N)      // prefetch; completes under vmcnt(0)
            nsv = (int)csr16[(size_t)nnode * CAP + lane];

        float f[8];
        #pragma unroll
        for (int j = 0; j < 8; ++j) f[j] = 0.f;

        if (node < N) {
            if (deg <= CAP) {
                for (int ch = 0; ch < deg; ch += 16) {
                    int nE = deg - ch; if (nE > 16) nE = 16;
                    int nL = (nE + 3) >> 2;
                    // close LDS WAR (prev ds_reads on stg) before restaging
                    asm volatile("s_waitcnt lgkmcnt(0)" ::: "memory");
                    __builtin_amdgcn_sched_barrier(0);
                    for (int l = 0; l < nL; ++l) {
                        int e = ch + l * 4 + eg;
                        int esel = (e < deg) ? e : (deg - 1);
                        int src = __shfl(sv, esel);
                        async_copy16((const char*)xh + ((size_t)src * 256 + (size_t)c * 16),
                                     stg + l * 1024);
                    }
                    asm volatile("s_waitcnt vmcnt(0)" ::: "memory");
                    __builtin_amdgcn_sched_barrier(0);
                    for (int l = 0; l < nL; ++l) {
                        uint4 v = *reinterpret_cast<const uint4*>(stg + l * 1024 + lane * 16);
                        if (ch + l * 4 + eg < deg) {
                            f[0] += __uint_as_float(v.x << 16);
                            f[1] += __uint_as_float(v.x & 0xffff0000u);
                            f[2] += __uint_as_float(v.y << 16);
                            f[3] += __uint_as_float(v.y & 0xffff0000u);
                            f[4] += __uint_as_float(v.z << 16);
                            f[5] += __uint_as_float(v.z & 0xffff0000u);
                            f[6] += __uint_as_float(v.w << 16);
                            f[7] += __uint_as_float(v.w & 0xffff0000u);
                        }
                    }
                }
            } else {
                // overflow (adversarial only): ballot-scan the full edge list
                int or_hi = 0;
                {
                    int lim = 2 * E; if (lim > 16) lim = 16;
                    for (int j = 1; j < lim; j += 2) or_hi |= ei[j];
                }
                const int is64 = (or_hi == 0) ? 1 : 0;
                for (int base = 0; base < E; base += 64) {
                    int e = base + lane;
                    int ss = 0, dd = -1;
                    if (e < E) load_edge(ei, is64, E, e, ss, dd);
                    unsigned long long m = __ballot(dd == node);
                    while (m) {
                        int i = __ffsll((long long)m) - 1;
                        m &= m - 1;
                        int sb = __shfl(ss, i);
                        if (eg == 0) {
                            uint4 v = reinterpret_cast<const uint4*>(xh)[(size_t)sb * 16 + c];
                            f[0] += __uint_as_float(v.x << 16);
                            f[1] += __uint_as_float(v.x & 0xffff0000u);
                            f[2] += __uint_as_float(v.y << 16);
                            f[3] += __uint_as_float(v.y & 0xffff0000u);
                            f[4] += __uint_as_float(v.z << 16);
                            f[5] += __uint_as_float(v.z & 0xffff0000u);
                            f[6] += __uint_as_float(v.w << 16);
                            f[7] += __uint_as_float(v.w & 0xffff0000u);
                        }
                    }
                }
            }
        }
        // reduce across the 4 edge-groups, write bf16 A-tile row
        #pragma unroll
        for (int j = 0; j < 8; ++j) {
            f[j] += __shfl_xor(f[j], 16);
            f[j] += __shfl_xor(f[j], 32);
        }
        if (eg == 0) {
            uint4 o;
            o.x = pack2(f[0], f[1]);
            o.y = pack2(f[2], f[3]);
            o.z = pack2(f[4], f[5]);
            o.w = pack2(f[6], f[7]);
            *reinterpret_cast<uint4*>(&sA[ni][c * 8]) = o;
        }
        deg = ndeg; sv = nsv;
    }
    // single wave: compiler inserts lgkmcnt waits between sA writes and reads

    // ---- MFMA phase: 16x128 output tile; B-frags straight from Wt (L1) ----
    const int quad = lane >> 4, n15 = lane & 15;
    f32x4 acc[8];
    #pragma unroll
    for (int i = 0; i < 8; ++i) acc[i] = (f32x4){0.f, 0.f, 0.f, 0.f};

    #pragma unroll
    for (int kc = 0; kc < F; kc += 32) {
        bf16x8 af = *reinterpret_cast<const bf16x8*>(&sA[n15][kc + quad * 8]);
        #pragma unroll
        for (int nt = 0; nt < 8; ++nt) {
            bf16x8 bfr = *reinterpret_cast<const bf16x8*>(
                Wt + (size_t)(nt * 16 + n15) * F + kc + quad * 8);
            acc[nt] = __builtin_amdgcn_mfma_f32_16x16x32_bf16(af, bfr, acc[nt], 0, 0, 0);
        }
    }

    #pragma unroll
    for (int nt = 0; nt < 8; ++nt) {
        float bv = bias[nt * 16 + n15];
        #pragma unroll
        for (int reg = 0; reg < 4; ++reg) {
            int row = nbase + quad * 4 + reg;
            if (row < N)
                out[(size_t)row * F + nt * 16 + n15] = acc[nt][reg] + bv;
        }
    }
}

// ================= fallback tiers (smaller ws or huge N) =================
__global__ __launch_bounds__(256) void init_kernel(
    const int* __restrict__ ei, int* __restrict__ flag,
    int* __restrict__ zero_arr, int N)
{
    int i = blockIdx.x * 256 + threadIdx.x;
    if (i < N) zero_arr[i] = 0;
    if (i == 0) {
        int or_hi = ei[1] | ei[3] | ei[5] | ei[7] | ei[9] | ei[11] | ei[13] | ei[15];
        *flag = (or_hi == 0) ? 1 : 0;
    }
}

__global__ __launch_bounds__(256) void position_bucket_kernel(
    const int* __restrict__ ei, const int* __restrict__ flag_p,
    int* __restrict__ cursor, int* __restrict__ csr_src, int E)
{
    int e = blockIdx.x * 256 + threadIdx.x;
    if (e >= E) return;
    int s, d;
    load_edge(ei, *flag_p, E, e, s, d);
    int slot = atomicAdd(&cursor[d], 1);
    if (slot < CAP) csr_src[(size_t)d * CAP + slot] = s;
}

__global__ __launch_bounds__(256) void gather_bucket_f32_kernel(
    const float* __restrict__ x, const int* __restrict__ ei,
    const int* __restrict__ flag_p, const int* __restrict__ cursor,
    const int* __restrict__ csr_src, float* __restrict__ agg, int N, int E)
{
    int node = blockIdx.x * 4 + (threadIdx.x >> 6);
    if (node >= N) return;
    int lane = threadIdx.x & 63;
    int half = lane >> 5;
    int col = lane & 31;
    int deg = cursor[node];

    const float4* x4 = reinterpret_cast<const float4*>(x);
    float4 a0 = make_float4(0.f, 0.f, 0.f, 0.f);
    float4 a1 = make_float4(0.f, 0.f, 0.f, 0.f);

    if (deg <= CAP) {
        int sv = (lane < deg) ? csr_src[(size_t)node * CAP + lane] : 0;
        int i = 0;
        for (; i + 3 < deg; i += 4) {
            int e0 = __shfl(sv, i + half);
            int e1 = __shfl(sv, i + 2 + half);
            float4 v0 = x4[(size_t)e0 * 32 + col];
            float4 v1 = x4[(size_t)e1 * 32 + col];
            a0.x += v0.x; a0.y += v0.y; a0.z += v0.z; a0.w += v0.w;
            a1.x += v1.x; a1.y += v1.y; a1.z += v1.z; a1.w += v1.w;
        }
        for (; i + 1 < deg; i += 2) {
            int e0 = __shfl(sv, i + half);
            float4 v0 = x4[(size_t)e0 * 32 + col];
            a0.x += v0.x; a0.y += v0.y; a0.z += v0.z; a0.w += v0.w;
        }
        if (i < deg) {
            int e0 = __shfl(sv, i);
            if (half == 0) {
                float4 v = x4[(size_t)e0 * 32 + col];
                a0.x += v.x; a0.y += v.y; a0.z += v.z; a0.w += v.w;
            }
        }
    } else {
        int is64 = *flag_p;
        for (int base = 0; base < E; base += 64) {
            int e = base + lane;
            int s = 0, d = -1;
            if (e < E) load_edge(ei, is64, E, e, s, d);
            unsigned long long m = __ballot(d == node);
            while (m) {
                int i = __ffsll((long long)m) - 1;
                m &= m - 1;
                int sb = __shfl(s, i);
                float4 v = x4[(size_t)sb * 32 + col];
                if (half == 0) { a0.x += v.x; a0.y += v.y; a0.z += v.z; a0.w += v.w; }
            }
        }
    }
    a0.x += a1.x; a0.y += a1.y; a0.z += a1.z; a0.w += a1.w;
    a0.x += __shfl_xor(a0.x, 32);
    a0.y += __shfl_xor(a0.y, 32);
    a0.z += __shfl_xor(a0.z, 32);
    a0.w += __shfl_xor(a0.w, 32);
    if (half == 0)
        reinterpret_cast<float4*>(agg)[(size_t)node * 32 + col] = a0;
}

__global__ __launch_bounds__(256) void scatter_kernel(
    const float* __restrict__ x, const int* __restrict__ ei,
    const int* __restrict__ flag_p, float* __restrict__ agg, int E)
{
    int tid = blockIdx.x * 256 + threadIdx.x;
    int e = tid >> 5;
    if (e >= E) return;
    int c = (tid & 31) << 2;
    int s, d;
    load_edge(ei, *flag_p, E, e, s, d);
    float4 v = *reinterpret_cast<const float4*>(x + (size_t)s * F + c);
    float* o = agg + (size_t)d * F + c;
    unsafeAtomicAdd(o + 0, v.x);
    unsafeAtomicAdd(o + 1, v.y);
    unsafeAtomicAdd(o + 2, v.z);
    unsafeAtomicAdd(o + 3, v.w);
}

// in-place fallback VALU GEMM: io = io @ W + bias
__global__ __launch_bounds__(256) void gemm_kernel(
    float* __restrict__ io, const float* __restrict__ W,
    const float* __restrict__ bias, int N)
{
    __shared__ float sA[TR * LDA];
    __shared__ float sW[KC * LDW];
    const int t = threadIdx.x;
    const int row0 = blockIdx.x * TR;
    const int g = t & 7;
    const int r = t >> 3;

    float acc[2][16];
    #pragma unroll
    for (int i = 0; i < 2; ++i)
        #pragma unroll
        for (int j = 0; j < 16; ++j) acc[i][j] = 0.0f;

    for (int kc = 0; kc < F; kc += KC) {
        #pragma unroll
        for (int u = 0; u < 2; ++u) {
            int idx = u * 256 + t;
            int row = idx >> 3;
            int k4 = (idx & 7) * 4;
            int grow = row0 + row;
            float4 v = (grow < N)
                ? *reinterpret_cast<const float4*>(io + (size_t)grow * F + kc + k4)
                : make_float4(0.f, 0.f, 0.f, 0.f);
            *reinterpret_cast<float4*>(&sA[row * LDA + k4]) = v;
        }
        #pragma unroll
        for (int u = 0; u < 4; ++u) {
            int idx = u * 256 + t;
            int kk = idx >> 5;
            int f4 = (idx & 31) * 4;
            float4 v = *reinterpret_cast<const float4*>(W + (size_t)(kc + kk) * F + f4);
            int chunk = f4 >> 4;
            int within = f4 & 15;
            *reinterpret_cast<float4*>(&sW[kk * LDW + chunk * 20 + within]) = v;
        }
        __syncthreads();

        #pragma unroll 8
        for (int kk = 0; kk < KC; ++kk) {
            const float* wp = &sW[kk * LDW + g * 20];
            const float4 w0 = *reinterpret_cast<const float4*>(wp + 0);
            const float4 w1 = *reinterpret_cast<const float4*>(wp + 4);
            const float4 w2 = *reinterpret_cast<const float4*>(wp + 8);
            const float4 w3 = *reinterpret_cast<const float4*>(wp + 12);
            #pragma unroll
            for (int i = 0; i < 2; ++i) {
                const float xv = sA[(r * 2 + i) * LDA + kk];
                acc[i][0]  += xv * w0.x;  acc[i][1]  += xv * w0.y;
                acc[i][2]  += xv * w0.z;  acc[i][3]  += xv * w0.w;
                acc[i][4]  += xv * w1.x;  acc[i][5]  += xv * w1.y;
                acc[i][6]  += xv * w1.z;  acc[i][7]  += xv * w1.w;
                acc[i][8]  += xv * w2.x;  acc[i][9]  += xv * w2.y;
                acc[i][10] += xv * w2.z;  acc[i][11] += xv * w2.w;
                acc[i][12] += xv * w3.x;  acc[i][13] += xv * w3.y;
                acc[i][14] += xv * w3.z;  acc[i][15] += xv * w3.w;
            }
        }
        __syncthreads();
    }

    float bv[16];
    #pragma unroll
    for (int j = 0; j < 16; ++j) bv[j] = bias[g * 16 + j];
    #pragma unroll
    for (int i = 0; i < 2; ++i) {
        int row = row0 + r * 2 + i;
        if (row < N) {
            float* o = io + (size_t)row * F + g * 16;
            #pragma unroll
            for (int j4 = 0; j4 < 4; ++j4) {
                float4 v;
                v.x = acc[i][j4 * 4 + 0] + bv[j4 * 4 + 0];
                v.y = acc[i][j4 * 4 + 1] + bv[j4 * 4 + 1];
                v.z = acc[i][j4 * 4 + 2] + bv[j4 * 4 + 2];
                v.w = acc[i][j4 * 4 + 3] + bv[j4 * 4 + 3];
                *reinterpret_cast<float4*>(o + j4 * 4) = v;
            }
        }
    }
}

static inline size_t al16(size_t v) { return (v + 15) & ~(size_t)15; }

extern "C" void kernel_launch(void* const* d_in, const int* in_sizes, int n_in,
                              void* d_out, int out_size, void* d_ws, size_t ws_size,
                              hipStream_t stream) {
    const float* x  = (const float*)d_in[0];
    const int*   ei = (const int*)d_in[1];
    const float* W2 = (const float*)d_in[5];
    const float* b2 = (const float*)d_in[6];
    float* out = (float*)d_out;

    const int N = in_sizes[0] / F;   // 50000
    const int E = in_sizes[2];       // 600000
    const int nblk = (N + 255) / 256;
    const int M4 = N * (F / 4);      // float4 count for x
    const int eblk = (E + 255) / 256;

    // tier A layout: pad[64B] | cursor[N] i32 | csr16[N*CAP] u16 |
    //                xh[N*F/2] u32 | Wt[F*F] u16      (requires N <= 65536)
    char* wsb = (char*)d_ws;
    size_t off = 64;
    int* cursor = (int*)(wsb + off);
    off = al16(off + (size_t)N * 4);
    unsigned short* csr16 = (unsigned short*)(wsb + off);
    off = al16(off + (size_t)N * CAP * 2);
    unsigned int* xh = (unsigned int*)(wsb + off);
    off = al16(off + (size_t)N * (F / 2) * 4);
    unsigned short* Wt = (unsigned short*)(wsb + off);
    off += (size_t)F * F * 2;
    size_t needA = off;

    // tier B: flag[16], cursor[N], csr_src[N*CAP] i32
    size_t needB = (size_t)(16 + N + (size_t)N * CAP) * sizeof(int);

    if (ws_size >= needA && N <= 65536) {
        hipMemsetAsync(cursor, 0, (size_t)N * sizeof(int), stream);

        int gp = (M4 + 255) / 256;
        int ge = (((E + 3) / 4) + 255) / 256; if (ge > gp) gp = ge;
        int gw = (F * F + 255) / 256;         if (gw > gp) gp = gw;
        prep_pos_kernel<<<gp, 256, 0, stream>>>(
            ei, x, W2, cursor, csr16, xh, Wt, N, E, M4);

        gather_gemm64_kernel<<<(N + 15) / 16, 64, 0, stream>>>(
            xh, ei, cursor, csr16, Wt, b2, out, N, E);
    } else if (ws_size >= needB) {
        int* flag    = (int*)wsb;
        int* curs    = flag + 16;
        int* csr_src = curs + N;
        init_kernel<<<nblk, 256, 0, stream>>>(ei, flag, curs, N);
        position_bucket_kernel<<<eblk, 256, 0, stream>>>(ei, flag, curs, csr_src, E);
        gather_bucket_f32_kernel<<<(N + 3) / 4, 256, 0, stream>>>(
            x, ei, flag, curs, csr_src, out, N, E);
        gemm_kernel<<<(N + TR - 1) / TR, 256, 0, stream>>>(out, W2, b2, N);
    } else {
        int* flag = (int*)wsb;
        init_kernel<<<1, 64, 0, stream>>>(ei, flag, flag + 16, 0);
        hipMemsetAsync(out, 0, (size_t)N * F * sizeof(float), stream);
        scatter_kernel<<<(E * 32 + 255) / 256, 256, 0, stream>>>(x, ei, flag, out, E);
        gemm_kernel<<<(N + TR - 1) / TR, 256, 0, stream>>>(out, W2, b2, N);
    }
}

// Round 6
// 158.078 us; speedup vs baseline: 3.2523x; 1.0679x over previous
//
#include <hip/hip_runtime.h>

#define F 128
#define CAP 64    // bucket capacity per node (deg~Poisson(12), P(>64)~1e-30)
#define LDT 136   // sWt leading dim (bf16 elems)
#define TR 64     // fallback GEMM row tile
#define KC 32
#define LDA 36
#define LDW 160

typedef __attribute__((ext_vector_type(8))) short bf16x8;
typedef __attribute__((ext_vector_type(4))) float f32x4;

__device__ __forceinline__ unsigned short bf16r(float f)
{
    unsigned u = __float_as_uint(f);
    return (unsigned short)((u + 0x7fffu + ((u >> 16) & 1u)) >> 16);
}

__device__ __forceinline__ unsigned pack2(float a, float b)
{
    return (unsigned)bf16r(a) | ((unsigned)bf16r(b) << 16);
}

__device__ __forceinline__ void load_edge(const int* __restrict__ ei, int is64,
                                          int E, int e, int& s, int& d)
{
    if (is64) {
        s = reinterpret_cast<const int2*>(ei)[e].x;
        d = reinterpret_cast<const int2*>(ei)[(size_t)E + e].x;
    } else {
        s = ei[e];
        d = ei[E + e];
    }
}

__device__ __forceinline__ float4 bf16x4_to_f4(uint2 u)
{
    float4 f;
    f.x = __uint_as_float(u.x << 16);
    f.y = __uint_as_float(u.x & 0xffff0000u);
    f.z = __uint_as_float(u.y << 16);
    f.w = __uint_as_float(u.y & 0xffff0000u);
    return f;
}

// async 16B/lane global->LDS stage (1 KB per call per wave). LDS dest is
// wave-uniform base + lane*16 (HW rule); global src addr is per-lane.
__device__ __forceinline__ void async_copy16(const void* g, void* lds)
{
    __builtin_amdgcn_global_load_lds(
        (const __attribute__((address_space(1))) unsigned int*)g,
        (__attribute__((address_space(3))) unsigned int*)lds,
        16, 0, 0);
}

// ---------- tier A kernel 1: fused prep (x->bf16, W->W^T bf16) + positioning.
// cursor pre-zeroed by hipMemsetAsync. Edge positioning overlaps the x
// conversion (done by disjoint thread ranges of the same grid).
__global__ __launch_bounds__(256) void prep_pos_kernel(
    const int* __restrict__ ei, const float* __restrict__ x,
    const float* __restrict__ W, int* __restrict__ cursor,
    unsigned short* __restrict__ csr16, unsigned int* __restrict__ xh,
    unsigned short* __restrict__ Wt, int N, int E, int M4)
{
    const int tid = blockIdx.x * 256 + threadIdx.x;

    // x -> bf16, float4 (16B) loads, uint2 (8B) stores
    if (tid < M4) {
        float4 v = reinterpret_cast<const float4*>(x)[tid];
        uint2 o;
        o.x = pack2(v.x, v.y);
        o.y = pack2(v.z, v.w);
        reinterpret_cast<uint2*>(xh)[tid] = o;
    }
    // W -> Wt (transposed, bf16)
    if (tid < F * F) {
        int k = tid >> 7, n = tid & 127;
        Wt[n * F + k] = bf16r(W[tid]);
    }

    // edge positioning: 4 edges/thread, 4 independent atomic chains
    const int base = 4 * tid;
    if (base >= E) return;
    int or_hi = 0;
    {
        int lim = 2 * E; if (lim > 16) lim = 16;
        for (int j = 1; j < lim; j += 2) or_hi |= ei[j];
    }
    const int is64 = (or_hi == 0) ? 1 : 0;

    int s[4], d[4];
    int cnt;
    if (base + 3 < E && (E & 3) == 0) {
        cnt = 4;
        if (is64) {
            const int4* sp = reinterpret_cast<const int4*>(ei);
            int4 a = sp[tid * 2], b = sp[tid * 2 + 1];
            s[0] = a.x; s[1] = a.z; s[2] = b.x; s[3] = b.z;
            const int4* dp = reinterpret_cast<const int4*>(ei) + ((size_t)E >> 1);
            int4 c = dp[tid * 2], e4 = dp[tid * 2 + 1];
            d[0] = c.x; d[1] = c.z; d[2] = e4.x; d[3] = e4.z;
        } else {
            int4 sv = reinterpret_cast<const int4*>(ei)[tid];
            int4 dv = reinterpret_cast<const int4*>(ei + E)[tid];
            s[0] = sv.x; s[1] = sv.y; s[2] = sv.z; s[3] = sv.w;
            d[0] = dv.x; d[1] = dv.y; d[2] = dv.z; d[3] = dv.w;
        }
    } else {
        cnt = E - base; if (cnt > 4) cnt = 4;
        for (int j = 0; j < cnt; ++j) load_edge(ei, is64, E, base + j, s[j], d[j]);
        for (int j = cnt; j < 4; ++j) { s[j] = 0; d[j] = 0; }
    }

    int slot[4];
    #pragma unroll
    for (int j = 0; j < 4; ++j)
        slot[j] = (j < cnt) ? atomicAdd(&cursor[d[j]], 1) : CAP;
    #pragma unroll
    for (int j = 0; j < 4; ++j)
        if (slot[j] < CAP) csr16[(size_t)d[j] * CAP + slot[j]] = (unsigned short)s[j];
}

// ---------- tier A kernel 2 (R2-proven): async-LDS gather, one node/wave.
// 16KB LDS/block + launch_bounds(256,8) -> 8 blocks/CU = 32 waves/CU.
__global__ __launch_bounds__(256, 8) void gather_async_kernel(
    const unsigned int* __restrict__ xh, const int* __restrict__ ei,
    const int* __restrict__ cursor, const unsigned short* __restrict__ csr16,
    unsigned int* __restrict__ aggbf, int N, int E)
{
    __shared__ char stg[4][4096];   // 16 KB: per-wave 16-edge staging area
    const int node = blockIdx.x * 4 + (threadIdx.x >> 6);
    if (node >= N) return;
    const int wv   = threadIdx.x >> 6;
    const int lane = threadIdx.x & 63;
    const int eg   = lane >> 4;      // edge-group 0..3 within a 4-edge load
    const int c    = lane & 15;      // uint4 column: feats 8c..8c+7
    char* ldsW = &stg[wv][0];

    const int deg = cursor[node];

    if (deg <= CAP) {
        int sv = (lane < deg) ? (int)csr16[(size_t)node * CAP + lane] : 0;
        float f[8];
        #pragma unroll
        for (int j = 0; j < 8; ++j) f[j] = 0.f;

        for (int ch = 0; ch < deg; ch += 16) {
            int nE = deg - ch; if (nE > 16) nE = 16;
            int nL = (nE + 3) >> 2;
            if (ch > 0) {
                // close the LDS reuse race before overwriting the buffer
                asm volatile("s_waitcnt lgkmcnt(0)" ::: "memory");
                __builtin_amdgcn_sched_barrier(0);
            }
            for (int l = 0; l < nL; ++l) {
                int e = ch + l * 4 + eg;
                int esel = (e < deg) ? e : (deg - 1);
                int src = __shfl(sv, esel);
                async_copy16((const char*)xh + ((size_t)src * 256 + (size_t)c * 16),
                             ldsW + l * 1024);
            }
            asm volatile("s_waitcnt vmcnt(0)" ::: "memory");
            __builtin_amdgcn_sched_barrier(0);
            for (int l = 0; l < nL; ++l) {
                uint4 v = *reinterpret_cast<const uint4*>(ldsW + l * 1024 + lane * 16);
                if (ch + l * 4 + eg < deg) {
                    f[0] += __uint_as_float(v.x << 16);
                    f[1] += __uint_as_float(v.x & 0xffff0000u);
                    f[2] += __uint_as_float(v.y << 16);
                    f[3] += __uint_as_float(v.y & 0xffff0000u);
                    f[4] += __uint_as_float(v.z << 16);
                    f[5] += __uint_as_float(v.z & 0xffff0000u);
                    f[6] += __uint_as_float(v.w << 16);
                    f[7] += __uint_as_float(v.w & 0xffff0000u);
                }
            }
        }
        // reduce across the 4 edge-groups (lane xor 16, xor 32)
        #pragma unroll
        for (int j = 0; j < 8; ++j) {
            f[j] += __shfl_xor(f[j], 16);
            f[j] += __shfl_xor(f[j], 32);
        }
        if (eg == 0) {
            uint4 o;
            o.x = pack2(f[0], f[1]);
            o.y = pack2(f[2], f[3]);
            o.z = pack2(f[4], f[5]);
            o.w = pack2(f[6], f[7]);
            reinterpret_cast<uint4*>(aggbf)[(size_t)node * 16 + c] = o;
        }
    } else {
        // overflow (adversarial only): ballot-scan the full edge list
        const int half = lane >> 5, col = lane & 31;
        const uint2* x2 = reinterpret_cast<const uint2*>(xh);
        int or_hi = 0;
        {
            int lim = 2 * E; if (lim > 16) lim = 16;
            for (int j = 1; j < lim; j += 2) or_hi |= ei[j];
        }
        const int is64 = (or_hi == 0) ? 1 : 0;
        float4 a0 = make_float4(0.f, 0.f, 0.f, 0.f);
        for (int base = 0; base < E; base += 64) {
            int e = base + lane;
            int s = 0, d = -1;
            if (e < E) load_edge(ei, is64, E, e, s, d);
            unsigned long long m = __ballot(d == node);
            while (m) {
                int i = __ffsll((long long)m) - 1;
                m &= m - 1;
                int sb = __shfl(s, i);
                float4 v = bf16x4_to_f4(x2[(size_t)sb * 32 + col]);
                if (half == 0) { a0.x += v.x; a0.y += v.y; a0.z += v.z; a0.w += v.w; }
            }
        }
        a0.x += __shfl_xor(a0.x, 32);
        a0.y += __shfl_xor(a0.y, 32);
        a0.z += __shfl_xor(a0.z, 32);
        a0.w += __shfl_xor(a0.w, 32);
        if (half == 0) {
            uint2 o;
            o.x = pack2(a0.x, a0.y);
            o.y = pack2(a0.z, a0.w);
            reinterpret_cast<uint2*>(aggbf)[(size_t)node * 32 + col] = o;
        }
    }
}

// ---------- MFMA GEMM: out[N,128] = aggbf(bf16) @ W + bias (fp32 acc) -------
__global__ __launch_bounds__(256) void gemm_mfma_kernel(
    const unsigned short* __restrict__ aggbf, const unsigned short* __restrict__ Wt,
    const float* __restrict__ bias, float* __restrict__ out, int N)
{
    __shared__ unsigned short sWt[F * LDT];   // 34816 B
    const int t = threadIdx.x;

    const uint4* Wg = reinterpret_cast<const uint4*>(Wt);
    #pragma unroll
    for (int u = 0; u < 8; ++u) {
        int idx = u * 256 + t;       // 0..2047
        int n = idx >> 4;
        int c = idx & 15;
        *reinterpret_cast<uint4*>(&sWt[n * LDT + c * 8]) = Wg[idx];
    }
    __syncthreads();

    const int wv = t >> 6, lane = t & 63;
    const int quad = lane >> 4, n15 = lane & 15;
    const int rbase = blockIdx.x * 64 + wv * 16;

    f32x4 acc[8];
    #pragma unroll
    for (int i = 0; i < 8; ++i) acc[i] = (f32x4){0.f, 0.f, 0.f, 0.f};

    const int arow = rbase + n15;
    const bool aval = (arow < N);
    #pragma unroll
    for (int kc = 0; kc < F; kc += 32) {
        bf16x8 af;
        if (aval)
            af = *reinterpret_cast<const bf16x8*>(aggbf + (size_t)arow * F + kc + quad * 8);
        else
            af = (bf16x8){0, 0, 0, 0, 0, 0, 0, 0};
        #pragma unroll
        for (int nt = 0; nt < 8; ++nt) {
            bf16x8 bfr = *reinterpret_cast<const bf16x8*>(
                &sWt[(nt * 16 + n15) * LDT + kc + quad * 8]);
            acc[nt] = __builtin_amdgcn_mfma_f32_16x16x32_bf16(af, bfr, acc[nt], 0, 0, 0);
        }
    }

    #pragma unroll
    for (int nt = 0; nt < 8; ++nt) {
        float bv = bias[nt * 16 + n15];
        #pragma unroll
        for (int reg = 0; reg < 4; ++reg) {
            int row = rbase + quad * 4 + reg;
            if (row < N)
                out[(size_t)row * F + nt * 16 + n15] = acc[nt][reg] + bv;
        }
    }
}

// ================= fallback tiers (smaller ws or huge N) =================
__global__ __launch_bounds__(256) void init_kernel(
    const int* __restrict__ ei, int* __restrict__ flag,
    int* __restrict__ zero_arr, int N)
{
    int i = blockIdx.x * 256 + threadIdx.x;
    if (i < N) zero_arr[i] = 0;
    if (i == 0) {
        int or_hi = ei[1] | ei[3] | ei[5] | ei[7] | ei[9] | ei[11] | ei[13] | ei[15];
        *flag = (or_hi == 0) ? 1 : 0;
    }
}

__global__ __launch_bounds__(256) void position_bucket_kernel(
    const int* __restrict__ ei, const int* __restrict__ flag_p,
    int* __restrict__ cursor, int* __restrict__ csr_src, int E)
{
    int e = blockIdx.x * 256 + threadIdx.x;
    if (e >= E) return;
    int s, d;
    load_edge(ei, *flag_p, E, e, s, d);
    int slot = atomicAdd(&cursor[d], 1);
    if (slot < CAP) csr_src[(size_t)d * CAP + slot] = s;
}

__global__ __launch_bounds__(256) void gather_bucket_f32_kernel(
    const float* __restrict__ x, const int* __restrict__ ei,
    const int* __restrict__ flag_p, const int* __restrict__ cursor,
    const int* __restrict__ csr_src, float* __restrict__ agg, int N, int E)
{
    int node = blockIdx.x * 4 + (threadIdx.x >> 6);
    if (node >= N) return;
    int lane = threadIdx.x & 63;
    int half = lane >> 5;
    int col = lane & 31;
    int deg = cursor[node];

    const float4* x4 = reinterpret_cast<const float4*>(x);
    float4 a0 = make_float4(0.f, 0.f, 0.f, 0.f);
    float4 a1 = make_float4(0.f, 0.f, 0.f, 0.f);

    if (deg <= CAP) {
        int sv = (lane < deg) ? csr_src[(size_t)node * CAP + lane] : 0;
        int i = 0;
        for (; i + 3 < deg; i += 4) {
            int e0 = __shfl(sv, i + half);
            int e1 = __shfl(sv, i + 2 + half);
            float4 v0 = x4[(size_t)e0 * 32 + col];
            float4 v1 = x4[(size_t)e1 * 32 + col];
            a0.x += v0.x; a0.y += v0.y; a0.z += v0.z; a0.w += v0.w;
            a1.x += v1.x; a1.y += v1.y; a1.z += v1.z; a1.w += v1.w;
        }
        for (; i + 1 < deg; i += 2) {
            int e0 = __shfl(sv, i + half);
            float4 v0 = x4[(size_t)e0 * 32 + col];
            a0.x += v0.x; a0.y += v0.y; a0.z += v0.z; a0.w += v0.w;
        }
        if (i < deg) {
            int e0 = __shfl(sv, i);
            if (half == 0) {
                float4 v = x4[(size_t)e0 * 32 + col];
                a0.x += v.x; a0.y += v.y; a0.z += v.z; a0.w += v.w;
            }
        }
    } else {
        int is64 = *flag_p;
        for (int base = 0; base < E; base += 64) {
            int e = base + lane;
            int s = 0, d = -1;
            if (e < E) load_edge(ei, is64, E, e, s, d);
            unsigned long long m = __ballot(d == node);
            while (m) {
                int i = __ffsll((long long)m) - 1;
                m &= m - 1;
                int sb = __shfl(s, i);
                float4 v = x4[(size_t)sb * 32 + col];
                if (half == 0) { a0.x += v.x; a0.y += v.y; a0.z += v.z; a0.w += v.w; }
            }
        }
    }
    a0.x += a1.x; a0.y += a1.y; a0.z += a1.z; a0.w += a1.w;
    a0.x += __shfl_xor(a0.x, 32);
    a0.y += __shfl_xor(a0.y, 32);
    a0.z += __shfl_xor(a0.z, 32);
    a0.w += __shfl_xor(a0.w, 32);
    if (half == 0)
        reinterpret_cast<float4*>(agg)[(size_t)node * 32 + col] = a0;
}

__global__ __launch_bounds__(256) void scatter_kernel(
    const float* __restrict__ x, const int* __restrict__ ei,
    const int* __restrict__ flag_p, float* __restrict__ agg, int E)
{
    int tid = blockIdx.x * 256 + threadIdx.x;
    int e = tid >> 5;
    if (e >= E) return;
    int c = (tid & 31) << 2;
    int s, d;
    load_edge(ei, *flag_p, E, e, s, d);
    float4 v = *reinterpret_cast<const float4*>(x + (size_t)s * F + c);
    float* o = agg + (size_t)d * F + c;
    unsafeAtomicAdd(o + 0, v.x);
    unsafeAtomicAdd(o + 1, v.y);
    unsafeAtomicAdd(o + 2, v.z);
    unsafeAtomicAdd(o + 3, v.w);
}

// in-place fallback VALU GEMM: io = io @ W + bias
__global__ __launch_bounds__(256) void gemm_kernel(
    float* __restrict__ io, const float* __restrict__ W,
    const float* __restrict__ bias, int N)
{
    __shared__ float sA[TR * LDA];
    __shared__ float sW[KC * LDW];
    const int t = threadIdx.x;
    const int row0 = blockIdx.x * TR;
    const int g = t & 7;
    const int r = t >> 3;

    float acc[2][16];
    #pragma unroll
    for (int i = 0; i < 2; ++i)
        #pragma unroll
        for (int j = 0; j < 16; ++j) acc[i][j] = 0.0f;

    for (int kc = 0; kc < F; kc += KC) {
        #pragma unroll
        for (int u = 0; u < 2; ++u) {
            int idx = u * 256 + t;
            int row = idx >> 3;
            int k4 = (idx & 7) * 4;
            int grow = row0 + row;
            float4 v = (grow < N)
                ? *reinterpret_cast<const float4*>(io + (size_t)grow * F + kc + k4)
                : make_float4(0.f, 0.f, 0.f, 0.f);
            *reinterpret_cast<float4*>(&sA[row * LDA + k4]) = v;
        }
        #pragma unroll
        for (int u = 0; u < 4; ++u) {
            int idx = u * 256 + t;
            int kk = idx >> 5;
            int f4 = (idx & 31) * 4;
            float4 v = *reinterpret_cast<const float4*>(W + (size_t)(kc + kk) * F + f4);
            int chunk = f4 >> 4;
            int within = f4 & 15;
            *reinterpret_cast<float4*>(&sW[kk * LDW + chunk * 20 + within]) = v;
        }
        __syncthreads();

        #pragma unroll 8
        for (int kk = 0; kk < KC; ++kk) {
            const float* wp = &sW[kk * LDW + g * 20];
            const float4 w0 = *reinterpret_cast<const float4*>(wp + 0);
            const float4 w1 = *reinterpret_cast<const float4*>(wp + 4);
            const float4 w2 = *reinterpret_cast<const float4*>(wp + 8);
            const float4 w3 = *reinterpret_cast<const float4*>(wp + 12);
            #pragma unroll
            for (int i = 0; i < 2; ++i) {
                const float xv = sA[(r * 2 + i) * LDA + kk];
                acc[i][0]  += xv * w0.x;  acc[i][1]  += xv * w0.y;
                acc[i][2]  += xv * w0.z;  acc[i][3]  += xv * w0.w;
                acc[i][4]  += xv * w1.x;  acc[i][5]  += xv * w1.y;
                acc[i][6]  += xv * w1.z;  acc[i][7]  += xv * w1.w;
                acc[i][8]  += xv * w2.x;  acc[i][9]  += xv * w2.y;
                acc[i][10] += xv * w2.z;  acc[i][11] += xv * w2.w;
                acc[i][12] += xv * w3.x;  acc[i][13] += xv * w3.y;
                acc[i][14] += xv * w3.z;  acc[i][15] += xv * w3.w;
            }
        }
        __syncthreads();
    }

    float bv[16];
    #pragma unroll
    for (int j = 0; j < 16; ++j) bv[j] = bias[g * 16 + j];
    #pragma unroll
    for (int i = 0; i < 2; ++i) {
        int row = row0 + r * 2 + i;
        if (row < N) {
            float* o = io + (size_t)row * F + g * 16;
            #pragma unroll
            for (int j4 = 0; j4 < 4; ++j4) {
                float4 v;
                v.x = acc[i][j4 * 4 + 0] + bv[j4 * 4 + 0];
                v.y = acc[i][j4 * 4 + 1] + bv[j4 * 4 + 1];
                v.z = acc[i][j4 * 4 + 2] + bv[j4 * 4 + 2];
                v.w = acc[i][j4 * 4 + 3] + bv[j4 * 4 + 3];
                *reinterpret_cast<float4*>(o + j4 * 4) = v;
            }
        }
    }
}

static inline size_t al16(size_t v) { return (v + 15) & ~(size_t)15; }

extern "C" void kernel_launch(void* const* d_in, const int* in_sizes, int n_in,
                              void* d_out, int out_size, void* d_ws, size_t ws_size,
                              hipStream_t stream) {
    const float* x  = (const float*)d_in[0];
    const int*   ei = (const int*)d_in[1];
    const float* W2 = (const float*)d_in[5];
    const float* b2 = (const float*)d_in[6];
    float* out = (float*)d_out;

    const int N = in_sizes[0] / F;   // 50000
    const int E = in_sizes[2];       // 600000
    const int nblk = (N + 255) / 256;
    const int M4 = N * (F / 4);      // float4 count for x
    const int eblk = (E + 255) / 256;

    // tier A layout: pad[64B] | cursor[N] i32 | csr16[N*CAP] u16 |
    //                xh[N*F/2] u32 | Wt[F*F] u16 | aggbf[N*F/2] u32
    //                (requires N <= 65536)
    char* wsb = (char*)d_ws;
    size_t off = 64;
    int* cursor = (int*)(wsb + off);
    off = al16(off + (size_t)N * 4);
    unsigned short* csr16 = (unsigned short*)(wsb + off);
    off = al16(off + (size_t)N * CAP * 2);
    unsigned int* xh = (unsigned int*)(wsb + off);
    off = al16(off + (size_t)N * (F / 2) * 4);
    unsigned short* Wt = (unsigned short*)(wsb + off);
    off = al16(off + (size_t)F * F * 2);
    unsigned int* aggbf = (unsigned int*)(wsb + off);
    off += (size_t)N * (F / 2) * 4;
    size_t needA = off;

    // tier B: flag[16], cursor[N], csr_src[N*CAP] i32
    size_t needB = (size_t)(16 + N + (size_t)N * CAP) * sizeof(int);

    if (ws_size >= needA && N <= 65536) {
        hipMemsetAsync(cursor, 0, (size_t)N * sizeof(int), stream);

        int gp = (M4 + 255) / 256;
        int ge = (((E + 3) / 4) + 255) / 256; if (ge > gp) gp = ge;
        int gw = (F * F + 255) / 256;         if (gw > gp) gp = gw;
        prep_pos_kernel<<<gp, 256, 0, stream>>>(
            ei, x, W2, cursor, csr16, xh, Wt, N, E, M4);

        gather_async_kernel<<<(N + 3) / 4, 256, 0, stream>>>(
            xh, ei, cursor, csr16, aggbf, N, E);

        gemm_mfma_kernel<<<(N + 63) / 64, 256, 0, stream>>>(
            (const unsigned short*)aggbf, Wt, b2, out, N);
    } else if (ws_size >= needB) {
        int* flag    = (int*)wsb;
        int* curs    = flag + 16;
        int* csr_src = curs + N;
        init_kernel<<<nblk, 256, 0, stream>>>(ei, flag, curs, N);
        position_bucket_kernel<<<eblk, 256, 0, stream>>>(ei, flag, curs, csr_src, E);
        gather_bucket_f32_kernel<<<(N + 3) / 4, 256, 0, stream>>>(
            x, ei, flag, curs, csr_src, out, N, E);
        gemm_kernel<<<(N + TR - 1) / TR, 256, 0, stream>>>(out, W2, b2, N);
    } else {
        int* flag = (int*)wsb;
        init_kernel<<<1, 64, 0, stream>>>(ei, flag, flag + 16, 0);
        hipMemsetAsync(out, 0, (size_t)N * F * sizeof(float), stream);
        scatter_kernel<<<(E * 32 + 255) / 256, 256, 0, stream>>>(x, ei, flag, out, E);
        gemm_kernel<<<(N + TR - 1) / TR, 256, 0, stream>>>(out, W2, b2, N);
    }
}

// Round 7
// 157.144 us; speedup vs baseline: 3.2716x; 1.0059x over previous
//
#include <hip/hip_runtime.h>

#define F 128
#define CAP 64    // bucket capacity per node (deg~Poisson(12), P(>64)~1e-30)
#define LDT 136   // sWt leading dim (bf16 elems)
#define TR 64     // fallback GEMM row tile
#define KC 32
#define LDA 36
#define LDW 160

typedef __attribute__((ext_vector_type(8))) short bf16x8;
typedef __attribute__((ext_vector_type(4))) float f32x4;

__device__ __forceinline__ unsigned short bf16r(float f)
{
    unsigned u = __float_as_uint(f);
    return (unsigned short)((u + 0x7fffu + ((u >> 16) & 1u)) >> 16);
}

__device__ __forceinline__ unsigned pack2(float a, float b)
{
    return (unsigned)bf16r(a) | ((unsigned)bf16r(b) << 16);
}

__device__ __forceinline__ void load_edge(const int* __restrict__ ei, int is64,
                                          int E, int e, int& s, int& d)
{
    if (is64) {
        s = reinterpret_cast<const int2*>(ei)[e].x;
        d = reinterpret_cast<const int2*>(ei)[(size_t)E + e].x;
    } else {
        s = ei[e];
        d = ei[E + e];
    }
}

__device__ __forceinline__ float4 bf16x4_to_f4(uint2 u)
{
    float4 f;
    f.x = __uint_as_float(u.x << 16);
    f.y = __uint_as_float(u.x & 0xffff0000u);
    f.z = __uint_as_float(u.y << 16);
    f.w = __uint_as_float(u.y & 0xffff0000u);
    return f;
}

// async 16B/lane global->LDS stage (1 KB per call per wave). LDS dest is
// wave-uniform base + lane*16 (HW rule); global src addr is per-lane.
__device__ __forceinline__ void async_copy16(const void* g, void* lds)
{
    __builtin_amdgcn_global_load_lds(
        (const __attribute__((address_space(1))) unsigned int*)g,
        (__attribute__((address_space(3))) unsigned int*)lds,
        16, 0, 0);
}

// ---------- tier A kernel 1: fused prep (x->bf16, W->W^T bf16) + positioning.
// cursor pre-zeroed by hipMemsetAsync.
// Positioning is 1 edge/thread (2344 blocks ~ 9 blocks/CU vs the old 586) and
// the atomic is ISSUED BEFORE the independent conversion work so its latency
// overlaps the streaming loads. csr16 store pattern unchanged (A/B isolate).
__global__ __launch_bounds__(256) void prep_pos_kernel(
    const int* __restrict__ ei, const float* __restrict__ x,
    const float* __restrict__ W, int* __restrict__ cursor,
    unsigned short* __restrict__ csr16, unsigned int* __restrict__ xh,
    unsigned short* __restrict__ Wt, int N, int E, int M4)
{
    const int tid = blockIdx.x * 256 + threadIdx.x;

    // ---- edge positioning: issue atomic early ----
    int s = 0, d = 0, slot = CAP;
    const bool epos = (tid < E);
    if (epos) {
        int or_hi = 0;
        {
            int lim = 2 * E; if (lim > 16) lim = 16;
            for (int j = 1; j < lim; j += 2) or_hi |= ei[j];
        }
        const int is64 = (or_hi == 0) ? 1 : 0;
        load_edge(ei, is64, E, tid, s, d);
        slot = atomicAdd(&cursor[d], 1);
    }

    // ---- x -> bf16 (independent of the atomic; overlaps its latency) ----
    if (tid < M4) {
        float4 v = reinterpret_cast<const float4*>(x)[tid];
        uint2 o;
        o.x = pack2(v.x, v.y);
        o.y = pack2(v.z, v.w);
        reinterpret_cast<uint2*>(xh)[tid] = o;
    }
    // ---- W -> Wt (transposed, bf16) ----
    if (tid < F * F) {
        int k = tid >> 7, n = tid & 127;
        Wt[n * F + k] = bf16r(W[tid]);
    }

    // ---- complete the positioning scatter ----
    if (epos && slot < CAP)
        csr16[(size_t)d * CAP + slot] = (unsigned short)s;
}

// ---------- tier A kernel 2 (R2-proven): async-LDS gather, one node/wave.
// 16KB LDS/block + launch_bounds(256,8) -> 8 blocks/CU = 32 waves/CU.
__global__ __launch_bounds__(256, 8) void gather_async_kernel(
    const unsigned int* __restrict__ xh, const int* __restrict__ ei,
    const int* __restrict__ cursor, const unsigned short* __restrict__ csr16,
    unsigned int* __restrict__ aggbf, int N, int E)
{
    __shared__ char stg[4][4096];   // 16 KB: per-wave 16-edge staging area
    const int node = blockIdx.x * 4 + (threadIdx.x >> 6);
    if (node >= N) return;
    const int wv   = threadIdx.x >> 6;
    const int lane = threadIdx.x & 63;
    const int eg   = lane >> 4;      // edge-group 0..3 within a 4-edge load
    const int c    = lane & 15;      // uint4 column: feats 8c..8c+7
    char* ldsW = &stg[wv][0];

    const int deg = cursor[node];

    if (deg <= CAP) {
        int sv = (lane < deg) ? (int)csr16[(size_t)node * CAP + lane] : 0;
        float f[8];
        #pragma unroll
        for (int j = 0; j < 8; ++j) f[j] = 0.f;

        for (int ch = 0; ch < deg; ch += 16) {
            int nE = deg - ch; if (nE > 16) nE = 16;
            int nL = (nE + 3) >> 2;
            if (ch > 0) {
                // close the LDS reuse race before overwriting the buffer
                asm volatile("s_waitcnt lgkmcnt(0)" ::: "memory");
                __builtin_amdgcn_sched_barrier(0);
            }
            for (int l = 0; l < nL; ++l) {
                int e = ch + l * 4 + eg;
                int esel = (e < deg) ? e : (deg - 1);
                int src = __shfl(sv, esel);
                async_copy16((const char*)xh + ((size_t)src * 256 + (size_t)c * 16),
                             ldsW + l * 1024);
            }
            asm volatile("s_waitcnt vmcnt(0)" ::: "memory");
            __builtin_amdgcn_sched_barrier(0);
            for (int l = 0; l < nL; ++l) {
                uint4 v = *reinterpret_cast<const uint4*>(ldsW + l * 1024 + lane * 16);
                if (ch + l * 4 + eg < deg) {
                    f[0] += __uint_as_float(v.x << 16);
                    f[1] += __uint_as_float(v.x & 0xffff0000u);
                    f[2] += __uint_as_float(v.y << 16);
                    f[3] += __uint_as_float(v.y & 0xffff0000u);
                    f[4] += __uint_as_float(v.z << 16);
                    f[5] += __uint_as_float(v.z & 0xffff0000u);
                    f[6] += __uint_as_float(v.w << 16);
                    f[7] += __uint_as_float(v.w & 0xffff0000u);
                }
            }
        }
        // reduce across the 4 edge-groups (lane xor 16, xor 32)
        #pragma unroll
        for (int j = 0; j < 8; ++j) {
            f[j] += __shfl_xor(f[j], 16);
            f[j] += __shfl_xor(f[j], 32);
        }
        if (eg == 0) {
            uint4 o;
            o.x = pack2(f[0], f[1]);
            o.y = pack2(f[2], f[3]);
            o.z = pack2(f[4], f[5]);
            o.w = pack2(f[6], f[7]);
            reinterpret_cast<uint4*>(aggbf)[(size_t)node * 16 + c] = o;
        }
    } else {
        // overflow (adversarial only): ballot-scan the full edge list
        const int half = lane >> 5, col = lane & 31;
        const uint2* x2 = reinterpret_cast<const uint2*>(xh);
        int or_hi = 0;
        {
            int lim = 2 * E; if (lim > 16) lim = 16;
            for (int j = 1; j < lim; j += 2) or_hi |= ei[j];
        }
        const int is64 = (or_hi == 0) ? 1 : 0;
        float4 a0 = make_float4(0.f, 0.f, 0.f, 0.f);
        for (int base = 0; base < E; base += 64) {
            int e = base + lane;
            int s = 0, d = -1;
            if (e < E) load_edge(ei, is64, E, e, s, d);
            unsigned long long m = __ballot(d == node);
            while (m) {
                int i = __ffsll((long long)m) - 1;
                m &= m - 1;
                int sb = __shfl(s, i);
                float4 v = bf16x4_to_f4(x2[(size_t)sb * 32 + col]);
                if (half == 0) { a0.x += v.x; a0.y += v.y; a0.z += v.z; a0.w += v.w; }
            }
        }
        a0.x += __shfl_xor(a0.x, 32);
        a0.y += __shfl_xor(a0.y, 32);
        a0.z += __shfl_xor(a0.z, 32);
        a0.w += __shfl_xor(a0.w, 32);
        if (half == 0) {
            uint2 o;
            o.x = pack2(a0.x, a0.y);
            o.y = pack2(a0.z, a0.w);
            reinterpret_cast<uint2*>(aggbf)[(size_t)node * 32 + col] = o;
        }
    }
}

// ---------- MFMA GEMM: out[N,128] = aggbf(bf16) @ W + bias (fp32 acc) -------
__global__ __launch_bounds__(256) void gemm_mfma_kernel(
    const unsigned short* __restrict__ aggbf, const unsigned short* __restrict__ Wt,
    const float* __restrict__ bias, float* __restrict__ out, int N)
{
    __shared__ unsigned short sWt[F * LDT];   // 34816 B
    const int t = threadIdx.x;

    const uint4* Wg = reinterpret_cast<const uint4*>(Wt);
    #pragma unroll
    for (int u = 0; u < 8; ++u) {
        int idx = u * 256 + t;       // 0..2047
        int n = idx >> 4;
        int c = idx & 15;
        *reinterpret_cast<uint4*>(&sWt[n * LDT + c * 8]) = Wg[idx];
    }
    __syncthreads();

    const int wv = t >> 6, lane = t & 63;
    const int quad = lane >> 4, n15 = lane & 15;
    const int rbase = blockIdx.x * 64 + wv * 16;

    f32x4 acc[8];
    #pragma unroll
    for (int i = 0; i < 8; ++i) acc[i] = (f32x4){0.f, 0.f, 0.f, 0.f};

    const int arow = rbase + n15;
    const bool aval = (arow < N);
    #pragma unroll
    for (int kc = 0; kc < F; kc += 32) {
        bf16x8 af;
        if (aval)
            af = *reinterpret_cast<const bf16x8*>(aggbf + (size_t)arow * F + kc + quad * 8);
        else
            af = (bf16x8){0, 0, 0, 0, 0, 0, 0, 0};
        #pragma unroll
        for (int nt = 0; nt < 8; ++nt) {
            bf16x8 bfr = *reinterpret_cast<const bf16x8*>(
                &sWt[(nt * 16 + n15) * LDT + kc + quad * 8]);
            acc[nt] = __builtin_amdgcn_mfma_f32_16x16x32_bf16(af, bfr, acc[nt], 0, 0, 0);
        }
    }

    #pragma unroll
    for (int nt = 0; nt < 8; ++nt) {
        float bv = bias[nt * 16 + n15];
        #pragma unroll
        for (int reg = 0; reg < 4; ++reg) {
            int row = rbase + quad * 4 + reg;
            if (row < N)
                out[(size_t)row * F + nt * 16 + n15] = acc[nt][reg] + bv;
        }
    }
}

// ================= fallback tiers (smaller ws or huge N) =================
__global__ __launch_bounds__(256) void init_kernel(
    const int* __restrict__ ei, int* __restrict__ flag,
    int* __restrict__ zero_arr, int N)
{
    int i = blockIdx.x * 256 + threadIdx.x;
    if (i < N) zero_arr[i] = 0;
    if (i == 0) {
        int or_hi = ei[1] | ei[3] | ei[5] | ei[7] | ei[9] | ei[11] | ei[13] | ei[15];
        *flag = (or_hi == 0) ? 1 : 0;
    }
}

__global__ __launch_bounds__(256) void position_bucket_kernel(
    const int* __restrict__ ei, const int* __restrict__ flag_p,
    int* __restrict__ cursor, int* __restrict__ csr_src, int E)
{
    int e = blockIdx.x * 256 + threadIdx.x;
    if (e >= E) return;
    int s, d;
    load_edge(ei, *flag_p, E, e, s, d);
    int slot = atomicAdd(&cursor[d], 1);
    if (slot < CAP) csr_src[(size_t)d * CAP + slot] = s;
}

__global__ __launch_bounds__(256) void gather_bucket_f32_kernel(
    const float* __restrict__ x, const int* __restrict__ ei,
    const int* __restrict__ flag_p, const int* __restrict__ cursor,
    const int* __restrict__ csr_src, float* __restrict__ agg, int N, int E)
{
    int node = blockIdx.x * 4 + (threadIdx.x >> 6);
    if (node >= N) return;
    int lane = threadIdx.x & 63;
    int half = lane >> 5;
    int col = lane & 31;
    int deg = cursor[node];

    const float4* x4 = reinterpret_cast<const float4*>(x);
    float4 a0 = make_float4(0.f, 0.f, 0.f, 0.f);
    float4 a1 = make_float4(0.f, 0.f, 0.f, 0.f);

    if (deg <= CAP) {
        int sv = (lane < deg) ? csr_src[(size_t)node * CAP + lane] : 0;
        int i = 0;
        for (; i + 3 < deg; i += 4) {
            int e0 = __shfl(sv, i + half);
            int e1 = __shfl(sv, i + 2 + half);
            float4 v0 = x4[(size_t)e0 * 32 + col];
            float4 v1 = x4[(size_t)e1 * 32 + col];
            a0.x += v0.x; a0.y += v0.y; a0.z += v0.z; a0.w += v0.w;
            a1.x += v1.x; a1.y += v1.y; a1.z += v1.z; a1.w += v1.w;
        }
        for (; i + 1 < deg; i += 2) {
            int e0 = __shfl(sv, i + half);
            float4 v0 = x4[(size_t)e0 * 32 + col];
            a0.x += v0.x; a0.y += v0.y; a0.z += v0.z; a0.w += v0.w;
        }
        if (i < deg) {
            int e0 = __shfl(sv, i);
            if (half == 0) {
                float4 v = x4[(size_t)e0 * 32 + col];
                a0.x += v.x; a0.y += v.y; a0.z += v.z; a0.w += v.w;
            }
        }
    } else {
        int is64 = *flag_p;
        for (int base = 0; base < E; base += 64) {
            int e = base + lane;
            int s = 0, d = -1;
            if (e < E) load_edge(ei, is64, E, e, s, d);
            unsigned long long m = __ballot(d == node);
            while (m) {
                int i = __ffsll((long long)m) - 1;
                m &= m - 1;
                int sb = __shfl(s, i);
                float4 v = x4[(size_t)sb * 32 + col];
                if (half == 0) { a0.x += v.x; a0.y += v.y; a0.z += v.z; a0.w += v.w; }
            }
        }
    }
    a0.x += a1.x; a0.y += a1.y; a0.z += a1.z; a0.w += a1.w;
    a0.x += __shfl_xor(a0.x, 32);
    a0.y += __shfl_xor(a0.y, 32);
    a0.z += __shfl_xor(a0.z, 32);
    a0.w += __shfl_xor(a0.w, 32);
    if (half == 0)
        reinterpret_cast<float4*>(agg)[(size_t)node * 32 + col] = a0;
}

__global__ __launch_bounds__(256) void scatter_kernel(
    const float* __restrict__ x, const int* __restrict__ ei,
    const int* __restrict__ flag_p, float* __restrict__ agg, int E)
{
    int tid = blockIdx.x * 256 + threadIdx.x;
    int e = tid >> 5;
    if (e >= E) return;
    int c = (tid & 31) << 2;
    int s, d;
    load_edge(ei, *flag_p, E, e, s, d);
    float4 v = *reinterpret_cast<const float4*>(x + (size_t)s * F + c);
    float* o = agg + (size_t)d * F + c;
    unsafeAtomicAdd(o + 0, v.x);
    unsafeAtomicAdd(o + 1, v.y);
    unsafeAtomicAdd(o + 2, v.z);
    unsafeAtomicAdd(o + 3, v.w);
}

// in-place fallback VALU GEMM: io = io @ W + bias
__global__ __launch_bounds__(256) void gemm_kernel(
    float* __restrict__ io, const float* __restrict__ W,
    const float* __restrict__ bias, int N)
{
    __shared__ float sA[TR * LDA];
    __shared__ float sW[KC * LDW];
    const int t = threadIdx.x;
    const int row0 = blockIdx.x * TR;
    const int g = t & 7;
    const int r = t >> 3;

    float acc[2][16];
    #pragma unroll
    for (int i = 0; i < 2; ++i)
        #pragma unroll
        for (int j = 0; j < 16; ++j) acc[i][j] = 0.0f;

    for (int kc = 0; kc < F; kc += KC) {
        #pragma unroll
        for (int u = 0; u < 2; ++u) {
            int idx = u * 256 + t;
            int row = idx >> 3;
            int k4 = (idx & 7) * 4;
            int grow = row0 + row;
            float4 v = (grow < N)
                ? *reinterpret_cast<const float4*>(io + (size_t)grow * F + kc + k4)
                : make_float4(0.f, 0.f, 0.f, 0.f);
            *reinterpret_cast<float4*>(&sA[row * LDA + k4]) = v;
        }
        #pragma unroll
        for (int u = 0; u < 4; ++u) {
            int idx = u * 256 + t;
            int kk = idx >> 5;
            int f4 = (idx & 31) * 4;
            float4 v = *reinterpret_cast<const float4*>(W + (size_t)(kc + kk) * F + f4);
            int chunk = f4 >> 4;
            int within = f4 & 15;
            *reinterpret_cast<float4*>(&sW[kk * LDW + chunk * 20 + within]) = v;
        }
        __syncthreads();

        #pragma unroll 8
        for (int kk = 0; kk < KC; ++kk) {
            const float* wp = &sW[kk * LDW + g * 20];
            const float4 w0 = *reinterpret_cast<const float4*>(wp + 0);
            const float4 w1 = *reinterpret_cast<const float4*>(wp + 4);
            const float4 w2 = *reinterpret_cast<const float4*>(wp + 8);
            const float4 w3 = *reinterpret_cast<const float4*>(wp + 12);
            #pragma unroll
            for (int i = 0; i < 2; ++i) {
                const float xv = sA[(r * 2 + i) * LDA + kk];
                acc[i][0]  += xv * w0.x;  acc[i][1]  += xv * w0.y;
                acc[i][2]  += xv * w0.z;  acc[i][3]  += xv * w0.w;
                acc[i][4]  += xv * w1.x;  acc[i][5]  += xv * w1.y;
                acc[i][6]  += xv * w1.z;  acc[i][7]  += xv * w1.w;
                acc[i][8]  += xv * w2.x;  acc[i][9]  += xv * w2.y;
                acc[i][10] += xv * w2.z;  acc[i][11] += xv * w2.w;
                acc[i][12] += xv * w3.x;  acc[i][13] += xv * w3.y;
                acc[i][14] += xv * w3.z;  acc[i][15] += xv * w3.w;
            }
        }
        __syncthreads();
    }

    float bv[16];
    #pragma unroll
    for (int j = 0; j < 16; ++j) bv[j] = bias[g * 16 + j];
    #pragma unroll
    for (int i = 0; i < 2; ++i) {
        int row = row0 + r * 2 + i;
        if (row < N) {
            float* o = io + (size_t)row * F + g * 16;
            #pragma unroll
            for (int j4 = 0; j4 < 4; ++j4) {
                float4 v;
                v.x = acc[i][j4 * 4 + 0] + bv[j4 * 4 + 0];
                v.y = acc[i][j4 * 4 + 1] + bv[j4 * 4 + 1];
                v.z = acc[i][j4 * 4 + 2] + bv[j4 * 4 + 2];
                v.w = acc[i][j4 * 4 + 3] + bv[j4 * 4 + 3];
                *reinterpret_cast<float4*>(o + j4 * 4) = v;
            }
        }
    }
}

static inline size_t al16(size_t v) { return (v + 15) & ~(size_t)15; }

extern "C" void kernel_launch(void* const* d_in, const int* in_sizes, int n_in,
                              void* d_out, int out_size, void* d_ws, size_t ws_size,
                              hipStream_t stream) {
    const float* x  = (const float*)d_in[0];
    const int*   ei = (const int*)d_in[1];
    const float* W2 = (const float*)d_in[5];
    const float* b2 = (const float*)d_in[6];
    float* out = (float*)d_out;

    const int N = in_sizes[0] / F;   // 50000
    const int E = in_sizes[2];       // 600000
    const int nblk = (N + 255) / 256;
    const int M4 = N * (F / 4);      // float4 count for x
    const int eblk = (E + 255) / 256;

    // tier A layout: pad[64B] | cursor[N] i32 | csr16[N*CAP] u16 |
    //                xh[N*F/2] u32 | Wt[F*F] u16 | aggbf[N*F/2] u32
    //                (requires N <= 65536)
    char* wsb = (char*)d_ws;
    size_t off = 64;
    int* cursor = (int*)(wsb + off);
    off = al16(off + (size_t)N * 4);
    unsigned short* csr16 = (unsigned short*)(wsb + off);
    off = al16(off + (size_t)N * CAP * 2);
    unsigned int* xh = (unsigned int*)(wsb + off);
    off = al16(off + (size_t)N * (F / 2) * 4);
    unsigned short* Wt = (unsigned short*)(wsb + off);
    off = al16(off + (size_t)F * F * 2);
    unsigned int* aggbf = (unsigned int*)(wsb + off);
    off += (size_t)N * (F / 2) * 4;
    size_t needA = off;

    // tier B: flag[16], cursor[N], csr_src[N*CAP] i32
    size_t needB = (size_t)(16 + N + (size_t)N * CAP) * sizeof(int);

    if (ws_size >= needA && N <= 65536) {
        hipMemsetAsync(cursor, 0, (size_t)N * sizeof(int), stream);

        int gp = (M4 + 255) / 256;
        int ge = (E + 255) / 256;             if (ge > gp) gp = ge;
        int gw = (F * F + 255) / 256;         if (gw > gp) gp = gw;
        prep_pos_kernel<<<gp, 256, 0, stream>>>(
            ei, x, W2, cursor, csr16, xh, Wt, N, E, M4);

        gather_async_kernel<<<(N + 3) / 4, 256, 0, stream>>>(
            xh, ei, cursor, csr16, aggbf, N, E);

        gemm_mfma_kernel<<<(N + 63) / 64, 256, 0, stream>>>(
            (const unsigned short*)aggbf, Wt, b2, out, N);
    } else if (ws_size >= needB) {
        int* flag    = (int*)wsb;
        int* curs    = flag + 16;
        int* csr_src = curs + N;
        init_kernel<<<nblk, 256, 0, stream>>>(ei, flag, curs, N);
        position_bucket_kernel<<<eblk, 256, 0, stream>>>(ei, flag, curs, csr_src, E);
        gather_bucket_f32_kernel<<<(N + 3) / 4, 256, 0, stream>>>(
            x, ei, flag, curs, csr_src, out, N, E);
        gemm_kernel<<<(N + TR - 1) / TR, 256, 0, stream>>>(out, W2, b2, N);
    } else {
        int* flag = (int*)wsb;
        init_kernel<<<1, 64, 0, stream>>>(ei, flag, flag + 16, 0);
        hipMemsetAsync(out, 0, (size_t)N * F * sizeof(float), stream);
        scatter_kernel<<<(E * 32 + 255) / 256, 256, 0, stream>>>(x, ei, flag, out, E);
        gemm_kernel<<<(N + TR - 1) / TR, 256, 0, stream>>>(out, W2, b2, N);
    }
}